// Round 2
// baseline (2929.307 us; speedup 1.0000x reference)
//
#include <hip/hip_runtime.h>
#include <math.h>

namespace {

constexpr int N = 100000;
constexpr int E = 800000;
constexpr int S = 5000;
constexpr int C = 7;
constexpr int SCAN_CH = 2048;
constexpr int SCAN_NB = (N + SCAN_CH - 1) / SCAN_CH; // 49

typedef unsigned short u16;

__device__ __forceinline__ float b2f(u16 u) {
  return __uint_as_float(((unsigned int)u) << 16);
}
__device__ __forceinline__ u16 f2b(float f) {
  unsigned int u = __float_as_uint(f);
  return (u16)((u + 0x7fffu + ((u >> 16) & 1u)) >> 16); // RNE
}

// ---------------- CSR build ----------------

__global__ void hist_kernel(const int* __restrict__ col, int* __restrict__ cnt) {
  int e = blockIdx.x * blockDim.x + threadIdx.x;
  if (e < E) atomicAdd(&cnt[col[e]], 1);
}

__global__ void dis_kernel(const int* __restrict__ cnt, float* __restrict__ dis) {
  int i = blockIdx.x * blockDim.x + threadIdx.x;
  if (i < N) dis[i] = rsqrtf((float)cnt[i] + 1.0f); // +1 self loop
}

__global__ void scan_sum_kernel(const int* __restrict__ cnt, int* __restrict__ bsum) {
  __shared__ int sh[256];
  int base = blockIdx.x * SCAN_CH;
  int s = 0;
  for (int i = threadIdx.x; i < SCAN_CH; i += 256) {
    int g = base + i;
    s += (g < N) ? cnt[g] : 0;
  }
  sh[threadIdx.x] = s;
  __syncthreads();
  for (int o = 128; o > 0; o >>= 1) {
    if (threadIdx.x < o) sh[threadIdx.x] += sh[threadIdx.x + o];
    __syncthreads();
  }
  if (threadIdx.x == 0) bsum[blockIdx.x] = sh[0];
}

__global__ void scan_bsum_kernel(int* __restrict__ bsum) {
  if (threadIdx.x == 0 && blockIdx.x == 0) {
    int acc = 0;
    for (int i = 0; i < SCAN_NB; i++) { int v = bsum[i]; bsum[i] = acc; acc += v; }
  }
}

__global__ void scan_final_kernel(const int* __restrict__ cnt, const int* __restrict__ bsum,
                                  int* __restrict__ off, int* __restrict__ cur) {
  __shared__ int sh[256];
  int t = threadIdx.x;
  int base = blockIdx.x * SCAN_CH + t * 8;
  int loc[8];
  int s = 0;
#pragma unroll
  for (int j = 0; j < 8; j++) {
    int g = base + j;
    loc[j] = s;
    s += (g < N) ? cnt[g] : 0;
  }
  sh[t] = s;
  __syncthreads();
  for (int o = 1; o < 256; o <<= 1) {
    int v = (t >= o) ? sh[t - o] : 0;
    __syncthreads();
    sh[t] += v;
    __syncthreads();
  }
  int pre = bsum[blockIdx.x] + ((t > 0) ? sh[t - 1] : 0);
#pragma unroll
  for (int j = 0; j < 8; j++) {
    int g = base + j;
    if (g < N) { int v = pre + loc[j]; off[g] = v; cur[g] = v; }
  }
}

__global__ void csr_scatter_kernel(const int* __restrict__ row, const int* __restrict__ col,
                                   int* __restrict__ cur, int* __restrict__ csr) {
  int e = blockIdx.x * blockDim.x + threadIdx.x;
  if (e < E) {
    int c = col[e];
    int slot = atomicAdd(&cur[c], 1);
    csr[slot] = row[e];
  }
}

// ---------------- aggregation: out[i] = dis[i]*(sum_j dis[j]*in[j] + dis[i]*in[i]) ----
// one wave per node; fp32 input variant (layer 1, D=128) writes bf16

__global__ void agg_f32_kernel(const float* __restrict__ in, int ldin,
                               u16* __restrict__ out, int ldout,
                               const int* __restrict__ off, const int* __restrict__ cnt,
                               const int* __restrict__ csr, const float* __restrict__ dis,
                               int dv) {
  int w = (blockIdx.x * blockDim.x + threadIdx.x) >> 6;
  int lane = threadIdx.x & 63;
  if (w >= N || lane >= dv) return;
  float di = dis[w];
  int st = off[w];
  int ct = cnt[w];
  float4 acc = ((const float4*)(in + (size_t)w * ldin))[lane];
  acc.x *= di; acc.y *= di; acc.z *= di; acc.w *= di;
  for (int e = 0; e < ct; e++) {
    int sidx = csr[st + e];
    float ds = dis[sidx];
    float4 v = ((const float4*)(in + (size_t)sidx * ldin))[lane];
    acc.x += ds * v.x; acc.y += ds * v.y; acc.z += ds * v.z; acc.w += ds * v.w;
  }
  ushort4 o;
  o.x = f2b(di * acc.x); o.y = f2b(di * acc.y);
  o.z = f2b(di * acc.z); o.w = f2b(di * acc.w);
  ((ushort4*)(out + (size_t)w * ldout))[lane] = o;
}

// bf16 input variant (layer 2, D=256)

__global__ void agg_b16_kernel(const u16* __restrict__ in, int ldin,
                               u16* __restrict__ out, int ldout,
                               const int* __restrict__ off, const int* __restrict__ cnt,
                               const int* __restrict__ csr, const float* __restrict__ dis,
                               int dv) {
  int w = (blockIdx.x * blockDim.x + threadIdx.x) >> 6;
  int lane = threadIdx.x & 63;
  if (w >= N || lane >= dv) return;
  float di = dis[w];
  int st = off[w];
  int ct = cnt[w];
  ushort4 sv = ((const ushort4*)(in + (size_t)w * ldin))[lane];
  float4 acc;
  acc.x = di * b2f(sv.x); acc.y = di * b2f(sv.y);
  acc.z = di * b2f(sv.z); acc.w = di * b2f(sv.w);
  for (int e = 0; e < ct; e++) {
    int sidx = csr[st + e];
    float ds = dis[sidx];
    ushort4 v = ((const ushort4*)(in + (size_t)sidx * ldin))[lane];
    acc.x += ds * b2f(v.x); acc.y += ds * b2f(v.y);
    acc.z += ds * b2f(v.z); acc.w += ds * b2f(v.w);
  }
  ushort4 o;
  o.x = f2b(di * acc.x); o.y = f2b(di * acc.y);
  o.z = f2b(di * acc.z); o.w = f2b(di * acc.w);
  ((ushort4*)(out + (size_t)w * ldout))[lane] = o;
}

// ---------------- GEMM: C = act( [A1|A2] @ B + bias ) ----------------
// A1: M x K1 bf16 (lda1), A2: M x K2 bf16 (lda2, may be null/K2=0)
// B: (K1+K2) x 256 fp32 row-major. C: M x 256 bf16 (ldc). 64x64 tile/block.

__global__ void gemm_kernel(const u16* __restrict__ A1, int lda1, int K1,
                            const u16* __restrict__ A2, int lda2, int K2,
                            const float* __restrict__ B,
                            const float* __restrict__ bias,
                            u16* __restrict__ Cc, int ldc, int M, int relu) {
  __shared__ __align__(16) float As[16][64];
  __shared__ __align__(16) float Bs[16][64];
  int tx = threadIdx.x; // 0..15
  int ty = threadIdx.y; // 0..15
  int tid = ty * 16 + tx;
  int m0 = blockIdx.y * 64;
  int n0 = blockIdx.x * 64;
  float acc[4][4] = {};
  int a_r = tid >> 2;        // 0..63
  int a_c = (tid & 3) * 4;   // 0,4,8,12
  int b_r = tid >> 4;        // 0..15
  int b_c = (tid & 15) * 4;  // 0..60
  int Ktot = K1 + K2;
  for (int k0 = 0; k0 < Ktot; k0 += 16) {
    const u16* A; int lda; int kloc;
    if (k0 < K1) { A = A1; lda = lda1; kloc = k0; }
    else         { A = A2; lda = lda2; kloc = k0 - K1; }
    ushort4 av;
    if (m0 + a_r < M)
      av = *(const ushort4*)(A + (size_t)(m0 + a_r) * lda + kloc + a_c);
    else { av.x = 0; av.y = 0; av.z = 0; av.w = 0; }
    float4 bv = *(const float4*)(B + (size_t)(k0 + b_r) * 256 + n0 + b_c);
    __syncthreads();
    As[a_c + 0][a_r] = b2f(av.x);
    As[a_c + 1][a_r] = b2f(av.y);
    As[a_c + 2][a_r] = b2f(av.z);
    As[a_c + 3][a_r] = b2f(av.w);
    *(float4*)&Bs[b_r][b_c] = bv;
    __syncthreads();
#pragma unroll
    for (int kk = 0; kk < 16; kk++) {
      float4 a4 = *(const float4*)&As[kk][ty * 4];
      float4 b4 = *(const float4*)&Bs[kk][tx * 4];
      float aa[4] = {a4.x, a4.y, a4.z, a4.w};
      float bb[4] = {b4.x, b4.y, b4.z, b4.w};
#pragma unroll
      for (int i = 0; i < 4; i++)
#pragma unroll
        for (int j = 0; j < 4; j++)
          acc[i][j] += aa[i] * bb[j];
    }
  }
#pragma unroll
  for (int i = 0; i < 4; i++) {
    int r = m0 + ty * 4 + i;
    if (r < M) {
      int cbase = n0 + tx * 4;
      float o[4];
#pragma unroll
      for (int j = 0; j < 4; j++) {
        o[j] = acc[i][j] + bias[cbase + j];
        if (relu) o[j] = fmaxf(o[j], 0.f);
      }
      ushort4 ov;
      ov.x = f2b(o[0]); ov.y = f2b(o[1]); ov.z = f2b(o[2]); ov.w = f2b(o[3]);
      *(ushort4*)(Cc + (size_t)r * ldc + cbase) = ov;
    }
  }
}

// ---------------- pooling ----------------

__global__ void pool_kernel(const u16* __restrict__ h, const int* __restrict__ idx,
                            float* __restrict__ P, float* __restrict__ pcnt, int coloff) {
  int t = blockIdx.x * blockDim.x + threadIdx.x;
  int node = t >> 6;
  int g = t & 63;
  if (node >= N) return;
  int seg = idx[node];
  ushort4 v = ((const ushort4*)(h + (size_t)node * 256))[g];
  float* dst = P + (size_t)seg * 512 + coloff + g * 4;
  atomicAdd(dst + 0, b2f(v.x));
  atomicAdd(dst + 1, b2f(v.y));
  atomicAdd(dst + 2, b2f(v.z));
  atomicAdd(dst + 3, b2f(v.w));
  if (g == 0) atomicAdd(&pcnt[seg], 1.0f);
}

__global__ void pool_div_kernel(const float* __restrict__ P, const float* __restrict__ c1,
                                const float* __restrict__ c2, u16* __restrict__ Pb) {
  int i = blockIdx.x * blockDim.x + threadIdx.x;
  if (i >= S * 512) return;
  int s = i >> 9;
  int f = i & 511;
  float c = (f < 256) ? c1[s] : c2[s];
  Pb[i] = f2b(P[i] / fmaxf(c, 1.0f));
}

// ---------------- classifier head: logits (256->7) + log_softmax ----------------

__global__ void final_kernel(const u16* __restrict__ PH, const float* __restrict__ w2,
                             const float* __restrict__ b2, float* __restrict__ out) {
  int wv = (blockIdx.x * blockDim.x + threadIdx.x) >> 6;
  int lane = threadIdx.x & 63;
  if (wv >= S) return;
  ushort4 hv = ((const ushort4*)(PH + (size_t)wv * 256))[lane];
  float hx = b2f(hv.x), hy = b2f(hv.y), hz = b2f(hv.z), hw = b2f(hv.w);
  int k = lane * 4;
  float lg[C];
#pragma unroll
  for (int c = 0; c < C; c++) {
    float p = hx * w2[(k + 0) * C + c] + hy * w2[(k + 1) * C + c] +
              hz * w2[(k + 2) * C + c] + hw * w2[(k + 3) * C + c];
#pragma unroll
    for (int o = 32; o > 0; o >>= 1) p += __shfl_down(p, o);
    lg[c] = p;
  }
  if (lane == 0) {
    float mx = -1e30f;
#pragma unroll
    for (int c = 0; c < C; c++) { lg[c] += b2[c]; mx = fmaxf(mx, lg[c]); }
    float ssum = 0.f;
#pragma unroll
    for (int c = 0; c < C; c++) ssum += expf(lg[c] - mx);
    float ls = logf(ssum);
#pragma unroll
    for (int c = 0; c < C; c++) out[(size_t)wv * C + c] = lg[c] - mx - ls;
  }
}

} // anonymous namespace

extern "C" void kernel_launch(void* const* d_in, const int* in_sizes, int n_in,
                              void* d_out, int out_size, void* d_ws, size_t ws_size,
                              hipStream_t stream) {
  const float* x    = (const float*)d_in[0];
  const int*   ei1  = (const int*)d_in[1];
  const int*   ei2  = (const int*)d_in[2];
  const int*   idx1 = (const int*)d_in[3];
  const int*   idx2 = (const int*)d_in[4];
  const float* w11 = (const float*)d_in[5];  const float* b11 = (const float*)d_in[6];
  const float* w12 = (const float*)d_in[7];  const float* b12 = (const float*)d_in[8];
  const float* w21 = (const float*)d_in[9];  const float* b21 = (const float*)d_in[10];
  const float* w22 = (const float*)d_in[11]; const float* b22 = (const float*)d_in[12];
  const float* m1w1 = (const float*)d_in[13]; const float* m1b1 = (const float*)d_in[14];
  const float* m1w2 = (const float*)d_in[15]; const float* m1b2 = (const float*)d_in[16];
  const float* m2w1 = (const float*)d_in[17]; const float* m2b1 = (const float*)d_in[18];
  const float* m2w2 = (const float*)d_in[19]; const float* m2b2 = (const float*)d_in[20];
  const float* mw1 = (const float*)d_in[21]; const float* mb1 = (const float*)d_in[22];
  const float* mw2 = (const float*)d_in[23]; const float* mb2 = (const float*)d_in[24];
  float* out = (float*)d_out;
  (void)n_in; (void)in_sizes; (void)out_size;

  // ---- workspace carve-up (bytes, 256B-aligned blocks) ----
  char* base = (char*)d_ws;
  size_t p = 0;
  auto alloc = [&](size_t bytes) {
    void* r = base + p;
    p += (bytes + 255) & ~(size_t)255;
    return r;
  };
  u16* B1 = (u16*)alloc((size_t)N * 256 * 2);   // 51.2 MB
  u16* B2 = (u16*)alloc((size_t)N * 256 * 2);   // 51.2 MB
  u16* B3 = (u16*)alloc((size_t)N * 256 * 2);   // 51.2 MB
  float* dis1 = (float*)alloc((size_t)N * 4);
  float* dis2 = (float*)alloc((size_t)N * 4);
  int* cnt1 = (int*)alloc((size_t)N * 4);
  int* cnt2 = (int*)alloc((size_t)N * 4);
  int* off1 = (int*)alloc((size_t)N * 4);
  int* off2 = (int*)alloc((size_t)N * 4);
  int* cur1 = (int*)alloc((size_t)N * 4);
  int* cur2 = (int*)alloc((size_t)N * 4);
  int* csr1 = (int*)alloc((size_t)E * 4);
  int* csr2 = (int*)alloc((size_t)E * 4);
  int* bsum = (int*)alloc(256);
  float* PC  = (float*)alloc((size_t)S * 512 * 4);
  float* pc1 = (float*)alloc((size_t)S * 4);
  float* pc2 = (float*)alloc((size_t)S * 4);
  u16* PCb = (u16*)alloc((size_t)S * 512 * 2);
  u16* PH  = (u16*)alloc((size_t)S * 256 * 2);
  if (p > ws_size) return; // ws too small: fail cleanly (absmax), not a fault

  auto build_csr = [&](const int* ei, int* cnt, int* off, int* cur, int* csr, float* dis) {
    const int* row = ei;
    const int* col = ei + E;
    hipMemsetAsync(cnt, 0, N * sizeof(int), stream);
    hipLaunchKernelGGL(hist_kernel, dim3((E + 255) / 256), dim3(256), 0, stream, col, cnt);
    hipLaunchKernelGGL(dis_kernel, dim3((N + 255) / 256), dim3(256), 0, stream, cnt, dis);
    hipLaunchKernelGGL(scan_sum_kernel, dim3(SCAN_NB), dim3(256), 0, stream, cnt, bsum);
    hipLaunchKernelGGL(scan_bsum_kernel, dim3(1), dim3(1), 0, stream, bsum);
    hipLaunchKernelGGL(scan_final_kernel, dim3(SCAN_NB), dim3(256), 0, stream, cnt, bsum, off, cur);
    hipLaunchKernelGGL(csr_scatter_kernel, dim3((E + 255) / 256), dim3(256), 0, stream,
                       row, col, cur, csr);
  };

  auto gemm = [&](const u16* A1, int lda1, int K1, const u16* A2, int lda2, int K2,
                  const float* B, const float* bias, u16* Cc, int ldc, int M, int relu) {
    hipLaunchKernelGGL(gemm_kernel, dim3(4, (M + 63) / 64), dim3(16, 16), 0, stream,
                       A1, lda1, K1, A2, lda2, K2, B, bias, Cc, ldc, M, relu);
  };

  // ---- CSR for both edge lists ----
  build_csr(ei1, cnt1, off1, cur1, csr1, dis1);
  build_csr(ei2, cnt2, off2, cur2, csr2, dis2);

  // ---- layer 1: conv = agg-then-GEMM (A@(XW) == (A@X)@W) ----
  hipLaunchKernelGGL(agg_f32_kernel, dim3(N / 4), dim3(256), 0, stream,
                     x, 128, B3, 128, off1, cnt1, csr1, dis1, 32);
  gemm(B3, 128, 128, nullptr, 0, 0, w11, b11, B1, 256, N, 1);       // x1 -> B1
  hipLaunchKernelGGL(agg_f32_kernel, dim3(N / 4), dim3(256), 0, stream,
                     x, 128, B3, 128, off2, cnt2, csr2, dis2, 32);
  gemm(B3, 128, 128, nullptr, 0, 0, w12, b12, B2, 256, N, 1);       // x2 -> B2
  // mlp_1: Hm = relu([x1|x2]@m1w1 + b) ; h = Hm@m1w2 + b
  gemm(B1, 256, 256, B2, 256, 256, m1w1, m1b1, B3, 256, N, 1);      // Hm -> B3
  gemm(B3, 256, 256, nullptr, 0, 0, m1w2, m1b2, B1, 256, N, 0);     // h  -> B1

  // ---- layer 2 ----
  hipLaunchKernelGGL(agg_b16_kernel, dim3(N / 4), dim3(256), 0, stream,
                     B1, 256, B2, 256, off1, cnt1, csr1, dis1, 64);
  gemm(B2, 256, 256, nullptr, 0, 0, w21, b21, B3, 256, N, 1);       // y1 -> B3
  hipLaunchKernelGGL(agg_b16_kernel, dim3(N / 4), dim3(256), 0, stream,
                     B1, 256, B2, 256, off2, cnt2, csr2, dis2, 64);
  gemm(B2, 256, 256, nullptr, 0, 0, w22, b22, B1, 256, N, 1);       // y2 -> B1
  // mlp_2
  gemm(B3, 256, 256, B1, 256, 256, m2w1, m2b1, B2, 256, N, 1);      // Hm2 -> B2
  gemm(B2, 256, 256, nullptr, 0, 0, m2w2, m2b2, B3, 256, N, 0);     // h2 -> B3

  // ---- pooling (scatter-mean into concat buffer) ----
  hipMemsetAsync(PC, 0, (size_t)S * 512 * sizeof(float), stream);
  hipMemsetAsync(pc1, 0, S * sizeof(float), stream);
  hipMemsetAsync(pc2, 0, S * sizeof(float), stream);
  hipLaunchKernelGGL(pool_kernel, dim3((N * 64 + 255) / 256), dim3(256), 0, stream,
                     B3, idx1, PC, pc1, 0);
  hipLaunchKernelGGL(pool_kernel, dim3((N * 64 + 255) / 256), dim3(256), 0, stream,
                     B3, idx2, PC, pc2, 256);
  hipLaunchKernelGGL(pool_div_kernel, dim3((S * 512 + 255) / 256), dim3(256), 0, stream,
                     PC, pc1, pc2, PCb);

  // ---- classifier head ----
  gemm(PCb, 512, 512, nullptr, 0, 0, mw1, mb1, PH, 256, S, 1);
  hipLaunchKernelGGL(final_kernel, dim3((S + 3) / 4), dim3(256), 0, stream,
                     PH, mw2, mb2, out);
}

// Round 3
// 1870.626 us; speedup vs baseline: 1.5659x; 1.5659x over previous
//
#include <hip/hip_runtime.h>
#include <math.h>

namespace {

constexpr int N = 100000;
constexpr int E = 800000;
constexpr int S = 5000;
constexpr int C = 7;
constexpr int SCAN_CH = 2048;
constexpr int SCAN_NB = (N + SCAN_CH - 1) / SCAN_CH; // 49

typedef unsigned short u16;
typedef short bf16x8 __attribute__((ext_vector_type(8)));
typedef float f32x4 __attribute__((ext_vector_type(4)));

__device__ __forceinline__ float b2f(u16 u) {
  return __uint_as_float(((unsigned int)u) << 16);
}
__device__ __forceinline__ u16 f2b(float f) {
  unsigned int u = __float_as_uint(f);
  return (u16)((u + 0x7fffu + ((u >> 16) & 1u)) >> 16); // RNE
}

// ---------------- CSR build ----------------

__global__ void hist_kernel(const int* __restrict__ col, int* __restrict__ cnt) {
  int e = blockIdx.x * blockDim.x + threadIdx.x;
  if (e < E) atomicAdd(&cnt[col[e]], 1);
}

__global__ void dis_kernel(const int* __restrict__ cnt, float* __restrict__ dis) {
  int i = blockIdx.x * blockDim.x + threadIdx.x;
  if (i < N) dis[i] = rsqrtf((float)cnt[i] + 1.0f); // +1 self loop
}

__global__ void scan_sum_kernel(const int* __restrict__ cnt, int* __restrict__ bsum) {
  __shared__ int sh[256];
  int base = blockIdx.x * SCAN_CH;
  int s = 0;
  for (int i = threadIdx.x; i < SCAN_CH; i += 256) {
    int g = base + i;
    s += (g < N) ? cnt[g] : 0;
  }
  sh[threadIdx.x] = s;
  __syncthreads();
  for (int o = 128; o > 0; o >>= 1) {
    if (threadIdx.x < o) sh[threadIdx.x] += sh[threadIdx.x + o];
    __syncthreads();
  }
  if (threadIdx.x == 0) bsum[blockIdx.x] = sh[0];
}

__global__ void scan_bsum_kernel(int* __restrict__ bsum) {
  if (threadIdx.x == 0 && blockIdx.x == 0) {
    int acc = 0;
    for (int i = 0; i < SCAN_NB; i++) { int v = bsum[i]; bsum[i] = acc; acc += v; }
  }
}

__global__ void scan_final_kernel(const int* __restrict__ cnt, const int* __restrict__ bsum,
                                  int* __restrict__ off, int* __restrict__ cur) {
  __shared__ int sh[256];
  int t = threadIdx.x;
  int base = blockIdx.x * SCAN_CH + t * 8;
  int loc[8];
  int s = 0;
#pragma unroll
  for (int j = 0; j < 8; j++) {
    int g = base + j;
    loc[j] = s;
    s += (g < N) ? cnt[g] : 0;
  }
  sh[t] = s;
  __syncthreads();
  for (int o = 1; o < 256; o <<= 1) {
    int v = (t >= o) ? sh[t - o] : 0;
    __syncthreads();
    sh[t] += v;
    __syncthreads();
  }
  int pre = bsum[blockIdx.x] + ((t > 0) ? sh[t - 1] : 0);
#pragma unroll
  for (int j = 0; j < 8; j++) {
    int g = base + j;
    if (g < N) { int v = pre + loc[j]; off[g] = v; cur[g] = v; }
  }
}

__global__ void csr_scatter_kernel(const int* __restrict__ row, const int* __restrict__ col,
                                   int* __restrict__ cur, int* __restrict__ csr) {
  int e = blockIdx.x * blockDim.x + threadIdx.x;
  if (e < E) {
    int c = col[e];
    int slot = atomicAdd(&cur[c], 1);
    csr[slot] = row[e];
  }
}

// ---------------- converts ----------------

__global__ void f32_to_b16_kernel(const float* __restrict__ in, u16* __restrict__ out, int n4) {
  int t = blockIdx.x * blockDim.x + threadIdx.x;
  if (t >= n4) return;
  float4 v = ((const float4*)in)[t];
  ushort4 o;
  o.x = f2b(v.x); o.y = f2b(v.y); o.z = f2b(v.z); o.w = f2b(v.w);
  ((ushort4*)out)[t] = o;
}

// W fp32 [K x 256] row-major -> Wt bf16 [256 x K] (n-major, k-contiguous)
__global__ void wt_kernel(const float* __restrict__ W, u16* __restrict__ Wt, int K) {
  int t = blockIdx.x * blockDim.x + threadIdx.x;
  if (t >= K * 256) return;
  int k = t >> 8;
  int n = t & 255;
  Wt[(size_t)n * K + k] = f2b(W[t]);
}

// ---------------- aggregation ----------------
// out[i] = dis[i]*(sum_j dis[j]*in[j] + dis[i]*in[i]); one wave per node

__global__ void agg_f32_kernel(const float* __restrict__ in, int ldin,
                               u16* __restrict__ out, int ldout,
                               const int* __restrict__ off, const int* __restrict__ cnt,
                               const int* __restrict__ csr, const float* __restrict__ dis,
                               int dv) {
  int w = (blockIdx.x * blockDim.x + threadIdx.x) >> 6;
  int lane = threadIdx.x & 63;
  if (w >= N || lane >= dv) return;
  float di = dis[w];
  int st = off[w];
  int ct = cnt[w];
  float4 acc = ((const float4*)(in + (size_t)w * ldin))[lane];
  acc.x *= di; acc.y *= di; acc.z *= di; acc.w *= di;
  for (int e = 0; e < ct; e++) {
    int sidx = csr[st + e];
    float ds = dis[sidx];
    float4 v = ((const float4*)(in + (size_t)sidx * ldin))[lane];
    acc.x += ds * v.x; acc.y += ds * v.y; acc.z += ds * v.z; acc.w += ds * v.w;
  }
  ushort4 o;
  o.x = f2b(di * acc.x); o.y = f2b(di * acc.y);
  o.z = f2b(di * acc.z); o.w = f2b(di * acc.w);
  ((ushort4*)(out + (size_t)w * ldout))[lane] = o;
}

__global__ void agg_b16_kernel(const u16* __restrict__ in, int ldin,
                               u16* __restrict__ out, int ldout,
                               const int* __restrict__ off, const int* __restrict__ cnt,
                               const int* __restrict__ csr, const float* __restrict__ dis,
                               int dv) {
  int w = (blockIdx.x * blockDim.x + threadIdx.x) >> 6;
  int lane = threadIdx.x & 63;
  if (w >= N || lane >= dv) return;
  float di = dis[w];
  int st = off[w];
  int ct = cnt[w];
  ushort4 sv = ((const ushort4*)(in + (size_t)w * ldin))[lane];
  float4 acc;
  acc.x = di * b2f(sv.x); acc.y = di * b2f(sv.y);
  acc.z = di * b2f(sv.z); acc.w = di * b2f(sv.w);
  for (int e = 0; e < ct; e++) {
    int sidx = csr[st + e];
    float ds = dis[sidx];
    ushort4 v = ((const ushort4*)(in + (size_t)sidx * ldin))[lane];
    acc.x += ds * b2f(v.x); acc.y += ds * b2f(v.y);
    acc.z += ds * b2f(v.z); acc.w += ds * b2f(v.w);
  }
  ushort4 o;
  o.x = f2b(di * acc.x); o.y = f2b(di * acc.y);
  o.z = f2b(di * acc.z); o.w = f2b(di * acc.w);
  ((ushort4*)(out + (size_t)w * ldout))[lane] = o;
}

// ---------------- MFMA GEMM: C = act([A1|A2] @ W + bias), W as Wt[256][Ktot] ----
// 128x128 tile, 4 waves (2x2), each wave 64x64 via 4x4 mfma_f32_16x16x32_bf16.
// LDS rows padded to 72 bf16 to break bank conflicts.

__global__ __launch_bounds__(256, 3) void mfma_gemm_kernel(
    const u16* __restrict__ A1, int lda1, int K1,
    const u16* __restrict__ A2, int lda2, int K2,
    const u16* __restrict__ Wt,
    const float* __restrict__ bias,
    u16* __restrict__ Cc, int ldc, int M, int relu) {
  constexpr int LDP = 72;
  __shared__ __align__(16) u16 As[128 * LDP];
  __shared__ __align__(16) u16 Bs[128 * LDP];
  int tid = threadIdx.x;
  int lane = tid & 63;
  int wid = tid >> 6;
  int wr = wid >> 1, wc = wid & 1;
  int quad = lane >> 4;
  int l15 = lane & 15;
  int m0 = blockIdx.y * 128;
  int n0 = blockIdx.x * 128;
  int Ktot = K1 + K2;
  f32x4 acc[4][4];
#pragma unroll
  for (int i = 0; i < 4; i++)
#pragma unroll
    for (int j = 0; j < 4; j++)
      acc[i][j] = (f32x4){0.f, 0.f, 0.f, 0.f};
  int srow = tid >> 3;       // 0..31
  int scol = (tid & 7) * 8;  // 0,8,..,56
  for (int k0 = 0; k0 < Ktot; k0 += 64) {
    const u16* A; int lda; int kloc;
    if (k0 < K1) { A = A1; lda = lda1; kloc = k0; }
    else         { A = A2; lda = lda2; kloc = k0 - K1; }
    __syncthreads();
#pragma unroll
    for (int r = 0; r < 4; r++) {
      int row = r * 32 + srow;
      int gm = m0 + row;
      uint4 v = make_uint4(0u, 0u, 0u, 0u);
      if (gm < M) v = *(const uint4*)(A + (size_t)gm * lda + kloc + scol);
      *(uint4*)&As[row * LDP + scol] = v;
      uint4 w = *(const uint4*)(Wt + (size_t)(n0 + row) * Ktot + k0 + scol);
      *(uint4*)&Bs[row * LDP + scol] = w;
    }
    __syncthreads();
#pragma unroll
    for (int kk = 0; kk < 2; kk++) {
      bf16x8 af[4], bfr[4];
#pragma unroll
      for (int i = 0; i < 4; i++) {
        af[i]  = *(const bf16x8*)&As[(wr * 64 + i * 16 + l15) * LDP + kk * 32 + quad * 8];
        bfr[i] = *(const bf16x8*)&Bs[(wc * 64 + i * 16 + l15) * LDP + kk * 32 + quad * 8];
      }
#pragma unroll
      for (int i = 0; i < 4; i++)
#pragma unroll
        for (int j = 0; j < 4; j++)
          acc[i][j] = __builtin_amdgcn_mfma_f32_16x16x32_bf16(af[i], bfr[j], acc[i][j], 0, 0, 0);
    }
  }
  // epilogue: D row = quad*4+reg, col = lane&15 (per 16x16 fragment)
#pragma unroll
  for (int j = 0; j < 4; j++) {
    int col = n0 + wc * 64 + j * 16 + l15;
    float bv = bias[col];
#pragma unroll
    for (int i = 0; i < 4; i++) {
      int rbase = m0 + wr * 64 + i * 16 + quad * 4;
#pragma unroll
      for (int reg = 0; reg < 4; reg++) {
        int r = rbase + reg;
        if (r < M) {
          float o = acc[i][j][reg] + bv;
          if (relu) o = fmaxf(o, 0.f);
          Cc[(size_t)r * ldc + col] = f2b(o);
        }
      }
    }
  }
}

// ---------------- pooling ----------------

__global__ void pool_kernel(const u16* __restrict__ h, const int* __restrict__ idx,
                            float* __restrict__ P, float* __restrict__ pcnt, int coloff) {
  int t = blockIdx.x * blockDim.x + threadIdx.x;
  int node = t >> 6;
  int g = t & 63;
  if (node >= N) return;
  int seg = idx[node];
  ushort4 v = ((const ushort4*)(h + (size_t)node * 256))[g];
  float* dst = P + (size_t)seg * 512 + coloff + g * 4;
  atomicAdd(dst + 0, b2f(v.x));
  atomicAdd(dst + 1, b2f(v.y));
  atomicAdd(dst + 2, b2f(v.z));
  atomicAdd(dst + 3, b2f(v.w));
  if (g == 0) atomicAdd(&pcnt[seg], 1.0f);
}

__global__ void pool_div_kernel(const float* __restrict__ P, const float* __restrict__ c1,
                                const float* __restrict__ c2, u16* __restrict__ Pb) {
  int i = blockIdx.x * blockDim.x + threadIdx.x;
  if (i >= S * 512) return;
  int s = i >> 9;
  int f = i & 511;
  float c = (f < 256) ? c1[s] : c2[s];
  Pb[i] = f2b(P[i] / fmaxf(c, 1.0f));
}

// ---------------- classifier head: logits (256->7) + log_softmax ----------------

__global__ void final_kernel(const u16* __restrict__ PH, const float* __restrict__ w2,
                             const float* __restrict__ b2, float* __restrict__ out) {
  int wv = (blockIdx.x * blockDim.x + threadIdx.x) >> 6;
  int lane = threadIdx.x & 63;
  if (wv >= S) return;
  ushort4 hv = ((const ushort4*)(PH + (size_t)wv * 256))[lane];
  float hx = b2f(hv.x), hy = b2f(hv.y), hz = b2f(hv.z), hw = b2f(hv.w);
  int k = lane * 4;
  float lg[C];
#pragma unroll
  for (int c = 0; c < C; c++) {
    float p = hx * w2[(k + 0) * C + c] + hy * w2[(k + 1) * C + c] +
              hz * w2[(k + 2) * C + c] + hw * w2[(k + 3) * C + c];
#pragma unroll
    for (int o = 32; o > 0; o >>= 1) p += __shfl_down(p, o);
    lg[c] = p;
  }
  if (lane == 0) {
    float mx = -1e30f;
#pragma unroll
    for (int c = 0; c < C; c++) { lg[c] += b2[c]; mx = fmaxf(mx, lg[c]); }
    float ssum = 0.f;
#pragma unroll
    for (int c = 0; c < C; c++) ssum += expf(lg[c] - mx);
    float ls = logf(ssum);
#pragma unroll
    for (int c = 0; c < C; c++) out[(size_t)wv * C + c] = lg[c] - mx - ls;
  }
}

} // anonymous namespace

extern "C" void kernel_launch(void* const* d_in, const int* in_sizes, int n_in,
                              void* d_out, int out_size, void* d_ws, size_t ws_size,
                              hipStream_t stream) {
  const float* x    = (const float*)d_in[0];
  const int*   ei1  = (const int*)d_in[1];
  const int*   ei2  = (const int*)d_in[2];
  const int*   idx1 = (const int*)d_in[3];
  const int*   idx2 = (const int*)d_in[4];
  const float* w11 = (const float*)d_in[5];  const float* b11 = (const float*)d_in[6];
  const float* w12 = (const float*)d_in[7];  const float* b12 = (const float*)d_in[8];
  const float* w21 = (const float*)d_in[9];  const float* b21 = (const float*)d_in[10];
  const float* w22 = (const float*)d_in[11]; const float* b22 = (const float*)d_in[12];
  const float* m1w1 = (const float*)d_in[13]; const float* m1b1 = (const float*)d_in[14];
  const float* m1w2 = (const float*)d_in[15]; const float* m1b2 = (const float*)d_in[16];
  const float* m2w1 = (const float*)d_in[17]; const float* m2b1 = (const float*)d_in[18];
  const float* m2w2 = (const float*)d_in[19]; const float* m2b2 = (const float*)d_in[20];
  const float* mw1 = (const float*)d_in[21]; const float* mb1 = (const float*)d_in[22];
  const float* mw2 = (const float*)d_in[23]; const float* mb2 = (const float*)d_in[24];
  float* out = (float*)d_out;
  (void)n_in; (void)in_sizes; (void)out_size;

  // ---- workspace carve-up ----
  char* base = (char*)d_ws;
  size_t p = 0;
  auto alloc = [&](size_t bytes) {
    void* r = base + p;
    p += (bytes + 255) & ~(size_t)255;
    return r;
  };
  u16* B1 = (u16*)alloc((size_t)N * 256 * 2);
  u16* B2 = (u16*)alloc((size_t)N * 256 * 2);
  u16* B3 = (u16*)alloc((size_t)N * 256 * 2);
  float* dis1 = (float*)alloc((size_t)N * 4);
  float* dis2 = (float*)alloc((size_t)N * 4);
  int* cnt1 = (int*)alloc((size_t)N * 4);
  int* cnt2 = (int*)alloc((size_t)N * 4);
  int* off1 = (int*)alloc((size_t)N * 4);
  int* off2 = (int*)alloc((size_t)N * 4);
  int* cur1 = (int*)alloc((size_t)N * 4);
  int* cur2 = (int*)alloc((size_t)N * 4);
  int* csr1 = (int*)alloc((size_t)E * 4);
  int* csr2 = (int*)alloc((size_t)E * 4);
  int* bsum = (int*)alloc(256);
  float* PC  = (float*)alloc((size_t)S * 512 * 4);
  float* pc1 = (float*)alloc((size_t)S * 4);
  float* pc2 = (float*)alloc((size_t)S * 4);
  u16* PCb = (u16*)alloc((size_t)S * 512 * 2);
  u16* PH  = (u16*)alloc((size_t)S * 256 * 2);
  // transposed bf16 weights
  u16* w11t  = (u16*)alloc((size_t)256 * 128 * 2);
  u16* w12t  = (u16*)alloc((size_t)256 * 128 * 2);
  u16* m1w1t = (u16*)alloc((size_t)256 * 512 * 2);
  u16* m1w2t = (u16*)alloc((size_t)256 * 256 * 2);
  u16* w21t  = (u16*)alloc((size_t)256 * 256 * 2);
  u16* w22t  = (u16*)alloc((size_t)256 * 256 * 2);
  u16* m2w1t = (u16*)alloc((size_t)256 * 512 * 2);
  u16* m2w2t = (u16*)alloc((size_t)256 * 256 * 2);
  u16* mw1t  = (u16*)alloc((size_t)256 * 512 * 2);
  size_t p_base = p;
  u16* xb = (u16*)alloc((size_t)N * 128 * 2);   // bf16 copy of x (optional)
  bool use_xb = (p <= ws_size);
  if (p_base > ws_size) return; // ws too small: fail cleanly, not a fault

  auto build_csr = [&](const int* ei, int* cnt, int* off, int* cur, int* csr, float* dis) {
    const int* row = ei;
    const int* col = ei + E;
    hipMemsetAsync(cnt, 0, N * sizeof(int), stream);
    hipLaunchKernelGGL(hist_kernel, dim3((E + 255) / 256), dim3(256), 0, stream, col, cnt);
    hipLaunchKernelGGL(dis_kernel, dim3((N + 255) / 256), dim3(256), 0, stream, cnt, dis);
    hipLaunchKernelGGL(scan_sum_kernel, dim3(SCAN_NB), dim3(256), 0, stream, cnt, bsum);
    hipLaunchKernelGGL(scan_bsum_kernel, dim3(1), dim3(1), 0, stream, bsum);
    hipLaunchKernelGGL(scan_final_kernel, dim3(SCAN_NB), dim3(256), 0, stream, cnt, bsum, off, cur);
    hipLaunchKernelGGL(csr_scatter_kernel, dim3((E + 255) / 256), dim3(256), 0, stream,
                       row, col, cur, csr);
  };

  auto wtrans = [&](const float* W, u16* Wt, int K) {
    hipLaunchKernelGGL(wt_kernel, dim3(K), dim3(256), 0, stream, W, Wt, K);
  };

  auto gemm = [&](const u16* A1, int lda1, int K1, const u16* A2, int lda2, int K2,
                  const u16* Wt, const float* bias, u16* Cc, int M, int relu) {
    hipLaunchKernelGGL(mfma_gemm_kernel, dim3(2, (M + 127) / 128), dim3(256), 0, stream,
                       A1, lda1, K1, A2, lda2, K2, Wt, bias, Cc, 256, M, relu);
  };

  // ---- weight transposes (tiny) ----
  wtrans(w11, w11t, 128);
  wtrans(w12, w12t, 128);
  wtrans(m1w1, m1w1t, 512);
  wtrans(m1w2, m1w2t, 256);
  wtrans(w21, w21t, 256);
  wtrans(w22, w22t, 256);
  wtrans(m2w1, m2w1t, 512);
  wtrans(m2w2, m2w2t, 256);
  wtrans(mw1, mw1t, 512);

  // ---- CSR for both edge lists ----
  build_csr(ei1, cnt1, off1, cur1, csr1, dis1);
  build_csr(ei2, cnt2, off2, cur2, csr2, dis2);

  // ---- layer 1: conv = agg-then-GEMM (A@(XW) == (A@X)@W) ----
  if (use_xb) {
    hipLaunchKernelGGL(f32_to_b16_kernel, dim3((N * 128 / 4 + 255) / 256), dim3(256), 0, stream,
                       x, xb, N * 128 / 4);
    hipLaunchKernelGGL(agg_b16_kernel, dim3(N / 4), dim3(256), 0, stream,
                       xb, 128, B3, 128, off1, cnt1, csr1, dis1, 32);
  } else {
    hipLaunchKernelGGL(agg_f32_kernel, dim3(N / 4), dim3(256), 0, stream,
                       x, 128, B3, 128, off1, cnt1, csr1, dis1, 32);
  }
  gemm(B3, 128, 128, nullptr, 0, 0, w11t, b11, B1, N, 1);        // x1 -> B1
  if (use_xb) {
    hipLaunchKernelGGL(agg_b16_kernel, dim3(N / 4), dim3(256), 0, stream,
                       xb, 128, B3, 128, off2, cnt2, csr2, dis2, 32);
  } else {
    hipLaunchKernelGGL(agg_f32_kernel, dim3(N / 4), dim3(256), 0, stream,
                       x, 128, B3, 128, off2, cnt2, csr2, dis2, 32);
  }
  gemm(B3, 128, 128, nullptr, 0, 0, w12t, b12, B2, N, 1);        // x2 -> B2
  // mlp_1
  gemm(B1, 256, 256, B2, 256, 256, m1w1t, m1b1, B3, N, 1);       // Hm -> B3
  gemm(B3, 256, 256, nullptr, 0, 0, m1w2t, m1b2, B1, N, 0);      // h  -> B1

  // ---- layer 2 ----
  hipLaunchKernelGGL(agg_b16_kernel, dim3(N / 4), dim3(256), 0, stream,
                     B1, 256, B2, 256, off1, cnt1, csr1, dis1, 64);
  gemm(B2, 256, 256, nullptr, 0, 0, w21t, b21, B3, N, 1);        // y1 -> B3
  hipLaunchKernelGGL(agg_b16_kernel, dim3(N / 4), dim3(256), 0, stream,
                     B1, 256, B2, 256, off2, cnt2, csr2, dis2, 64);
  gemm(B2, 256, 256, nullptr, 0, 0, w22t, b22, B1, N, 1);        // y2 -> B1
  // mlp_2
  gemm(B3, 256, 256, B1, 256, 256, m2w1t, m2b1, B2, N, 1);       // Hm2 -> B2
  gemm(B2, 256, 256, nullptr, 0, 0, m2w2t, m2b2, B3, N, 0);      // h2 -> B3

  // ---- pooling (scatter-mean into concat buffer) ----
  hipMemsetAsync(PC, 0, (size_t)S * 512 * sizeof(float), stream);
  hipMemsetAsync(pc1, 0, S * sizeof(float), stream);
  hipMemsetAsync(pc2, 0, S * sizeof(float), stream);
  hipLaunchKernelGGL(pool_kernel, dim3((N * 64 + 255) / 256), dim3(256), 0, stream,
                     B3, idx1, PC, pc1, 0);
  hipLaunchKernelGGL(pool_kernel, dim3((N * 64 + 255) / 256), dim3(256), 0, stream,
                     B3, idx2, PC, pc2, 256);
  hipLaunchKernelGGL(pool_div_kernel, dim3((S * 512 + 255) / 256), dim3(256), 0, stream,
                     PC, pc1, pc2, PCb);

  // ---- classifier head ----
  gemm(PCb, 512, 512, nullptr, 0, 0, mw1t, mb1, PH, S, 1);
  hipLaunchKernelGGL(final_kernel, dim3((S + 3) / 4), dim3(256), 0, stream,
                     PH, mw2, mb2, out);
}

// Round 4
// 1274.801 us; speedup vs baseline: 2.2979x; 1.4674x over previous
//
#include <hip/hip_runtime.h>
#include <math.h>

namespace {

constexpr int N = 100000;
constexpr int E = 800000;
constexpr int S = 5000;
constexpr int C = 7;
constexpr int SCAN_CH = 2048;

typedef unsigned short u16;
typedef short bf16x8 __attribute__((ext_vector_type(8)));
typedef float f32x4 __attribute__((ext_vector_type(4)));

__device__ __forceinline__ float b2f(u16 u) {
  return __uint_as_float(((unsigned int)u) << 16);
}
__device__ __forceinline__ u16 f2b(float f) {
  unsigned int u = __float_as_uint(f);
  return (u16)((u + 0x7fffu + ((u >> 16) & 1u)) >> 16); // RNE
}

// ---------------- generic histogram / scan / scatter (CSR build) ----------------

__global__ void hist_kernel(const int* __restrict__ col, int* __restrict__ cnt, int n) {
  int e = blockIdx.x * blockDim.x + threadIdx.x;
  if (e < n) atomicAdd(&cnt[col[e]], 1);
}

__global__ void dis_kernel(const int* __restrict__ cnt, float* __restrict__ dis) {
  int i = blockIdx.x * blockDim.x + threadIdx.x;
  if (i < N) dis[i] = rsqrtf((float)cnt[i] + 1.0f); // +1 self loop
}

__global__ void scan_sum_kernel(const int* __restrict__ cnt, int* __restrict__ bsum, int n) {
  __shared__ int sh[256];
  int base = blockIdx.x * SCAN_CH;
  int s = 0;
  for (int i = threadIdx.x; i < SCAN_CH; i += 256) {
    int g = base + i;
    s += (g < n) ? cnt[g] : 0;
  }
  sh[threadIdx.x] = s;
  __syncthreads();
  for (int o = 128; o > 0; o >>= 1) {
    if (threadIdx.x < o) sh[threadIdx.x] += sh[threadIdx.x + o];
    __syncthreads();
  }
  if (threadIdx.x == 0) bsum[blockIdx.x] = sh[0];
}

__global__ void scan_bsum_kernel(int* __restrict__ bsum, int nb) {
  if (threadIdx.x == 0 && blockIdx.x == 0) {
    int acc = 0;
    for (int i = 0; i < nb; i++) { int v = bsum[i]; bsum[i] = acc; acc += v; }
  }
}

__global__ void scan_final_kernel(const int* __restrict__ cnt, const int* __restrict__ bsum,
                                  int* __restrict__ off, int* __restrict__ cur, int n) {
  __shared__ int sh[256];
  int t = threadIdx.x;
  int base = blockIdx.x * SCAN_CH + t * 8;
  int loc[8];
  int s = 0;
#pragma unroll
  for (int j = 0; j < 8; j++) {
    int g = base + j;
    loc[j] = s;
    s += (g < n) ? cnt[g] : 0;
  }
  sh[t] = s;
  __syncthreads();
  for (int o = 1; o < 256; o <<= 1) {
    int v = (t >= o) ? sh[t - o] : 0;
    __syncthreads();
    sh[t] += v;
    __syncthreads();
  }
  int pre = bsum[blockIdx.x] + ((t > 0) ? sh[t - 1] : 0);
#pragma unroll
  for (int j = 0; j < 8; j++) {
    int g = base + j;
    if (g < n) { int v = pre + loc[j]; off[g] = v; cur[g] = v; }
  }
}

// scatter edge sources: csr[slot of col[e]] = row[e]
__global__ void csr_scatter_kernel(const int* __restrict__ row, const int* __restrict__ col,
                                   int* __restrict__ cur, int* __restrict__ csr) {
  int e = blockIdx.x * blockDim.x + threadIdx.x;
  if (e < E) {
    int c = col[e];
    int slot = atomicAdd(&cur[c], 1);
    csr[slot] = row[e];
  }
}

// scatter node ids grouped by segment: pcsr[slot of idx[i]] = i
__global__ void pool_scatter_kernel(const int* __restrict__ idx, int* __restrict__ cur,
                                    int* __restrict__ pcsr) {
  int i = blockIdx.x * blockDim.x + threadIdx.x;
  if (i < N) {
    int s = idx[i];
    int slot = atomicAdd(&cur[s], 1);
    pcsr[slot] = i;
  }
}

// ---------------- converts ----------------

__global__ void f32_to_b16_kernel(const float* __restrict__ in, u16* __restrict__ out, int n4) {
  int t = blockIdx.x * blockDim.x + threadIdx.x;
  if (t >= n4) return;
  float4 v = ((const float4*)in)[t];
  ushort4 o;
  o.x = f2b(v.x); o.y = f2b(v.y); o.z = f2b(v.z); o.w = f2b(v.w);
  ((ushort4*)out)[t] = o;
}

// W fp32 [K x 256] row-major -> Wt bf16 [256 x K] (n-major, k-contiguous)
__global__ void wt_kernel(const float* __restrict__ W, u16* __restrict__ Wt, int K) {
  int t = blockIdx.x * blockDim.x + threadIdx.x;
  if (t >= K * 256) return;
  int k = t >> 8;
  int n = t & 255;
  Wt[(size_t)n * K + k] = f2b(W[t]);
}

// ---------------- aggregation ----------------
// out[i] = dis[i]*(sum_j dis[j]*in[j] + dis[i]*in[i]); one wave per node

__global__ void agg_f32_kernel(const float* __restrict__ in, int ldin,
                               u16* __restrict__ out, int ldout,
                               const int* __restrict__ off, const int* __restrict__ cnt,
                               const int* __restrict__ csr, const float* __restrict__ dis,
                               int dv) {
  int w = (blockIdx.x * blockDim.x + threadIdx.x) >> 6;
  int lane = threadIdx.x & 63;
  if (w >= N || lane >= dv) return;
  float di = dis[w];
  int st = off[w];
  int ct = cnt[w];
  float4 acc = ((const float4*)(in + (size_t)w * ldin))[lane];
  acc.x *= di; acc.y *= di; acc.z *= di; acc.w *= di;
  for (int e = 0; e < ct; e++) {
    int sidx = csr[st + e];
    float ds = dis[sidx];
    float4 v = ((const float4*)(in + (size_t)sidx * ldin))[lane];
    acc.x += ds * v.x; acc.y += ds * v.y; acc.z += ds * v.z; acc.w += ds * v.w;
  }
  ushort4 o;
  o.x = f2b(di * acc.x); o.y = f2b(di * acc.y);
  o.z = f2b(di * acc.z); o.w = f2b(di * acc.w);
  ((ushort4*)(out + (size_t)w * ldout))[lane] = o;
}

__global__ void agg_b16_kernel(const u16* __restrict__ in, int ldin,
                               u16* __restrict__ out, int ldout,
                               const int* __restrict__ off, const int* __restrict__ cnt,
                               const int* __restrict__ csr, const float* __restrict__ dis,
                               int dv) {
  int w = (blockIdx.x * blockDim.x + threadIdx.x) >> 6;
  int lane = threadIdx.x & 63;
  if (w >= N || lane >= dv) return;
  float di = dis[w];
  int st = off[w];
  int ct = cnt[w];
  ushort4 sv = ((const ushort4*)(in + (size_t)w * ldin))[lane];
  float4 acc;
  acc.x = di * b2f(sv.x); acc.y = di * b2f(sv.y);
  acc.z = di * b2f(sv.z); acc.w = di * b2f(sv.w);
  for (int e = 0; e < ct; e++) {
    int sidx = csr[st + e];
    float ds = dis[sidx];
    ushort4 v = ((const ushort4*)(in + (size_t)sidx * ldin))[lane];
    acc.x += ds * b2f(v.x); acc.y += ds * b2f(v.y);
    acc.z += ds * b2f(v.z); acc.w += ds * b2f(v.w);
  }
  ushort4 o;
  o.x = f2b(di * acc.x); o.y = f2b(di * acc.y);
  o.z = f2b(di * acc.z); o.w = f2b(di * acc.w);
  ((ushort4*)(out + (size_t)w * ldout))[lane] = o;
}

// ---------------- MFMA GEMM: C = act([A1|A2] @ W + bias), W as Wt[256][Ktot] ----
// 128x128 tile, 4 waves (2x2), each wave 64x64 via 4x4 mfma_f32_16x16x32_bf16.
// LDS rows padded to 72 bf16 to break bank conflicts.

__global__ __launch_bounds__(256, 3) void mfma_gemm_kernel(
    const u16* __restrict__ A1, int lda1, int K1,
    const u16* __restrict__ A2, int lda2, int K2,
    const u16* __restrict__ Wt,
    const float* __restrict__ bias,
    u16* __restrict__ Cc, int ldc, int M, int relu) {
  constexpr int LDP = 72;
  __shared__ __align__(16) u16 As[128 * LDP];
  __shared__ __align__(16) u16 Bs[128 * LDP];
  int tid = threadIdx.x;
  int lane = tid & 63;
  int wid = tid >> 6;
  int wr = wid >> 1, wc = wid & 1;
  int quad = lane >> 4;
  int l15 = lane & 15;
  int m0 = blockIdx.y * 128;
  int n0 = blockIdx.x * 128;
  int Ktot = K1 + K2;
  f32x4 acc[4][4];
#pragma unroll
  for (int i = 0; i < 4; i++)
#pragma unroll
    for (int j = 0; j < 4; j++)
      acc[i][j] = (f32x4){0.f, 0.f, 0.f, 0.f};
  int srow = tid >> 3;       // 0..31
  int scol = (tid & 7) * 8;  // 0,8,..,56
  for (int k0 = 0; k0 < Ktot; k0 += 64) {
    const u16* A; int lda; int kloc;
    if (k0 < K1) { A = A1; lda = lda1; kloc = k0; }
    else         { A = A2; lda = lda2; kloc = k0 - K1; }
    __syncthreads();
#pragma unroll
    for (int r = 0; r < 4; r++) {
      int row = r * 32 + srow;
      int gm = m0 + row;
      uint4 v = make_uint4(0u, 0u, 0u, 0u);
      if (gm < M) v = *(const uint4*)(A + (size_t)gm * lda + kloc + scol);
      *(uint4*)&As[row * LDP + scol] = v;
      uint4 w = *(const uint4*)(Wt + (size_t)(n0 + row) * Ktot + k0 + scol);
      *(uint4*)&Bs[row * LDP + scol] = w;
    }
    __syncthreads();
#pragma unroll
    for (int kk = 0; kk < 2; kk++) {
      bf16x8 af[4], bfr[4];
#pragma unroll
      for (int i = 0; i < 4; i++) {
        af[i]  = *(const bf16x8*)&As[(wr * 64 + i * 16 + l15) * LDP + kk * 32 + quad * 8];
        bfr[i] = *(const bf16x8*)&Bs[(wc * 64 + i * 16 + l15) * LDP + kk * 32 + quad * 8];
      }
#pragma unroll
      for (int i = 0; i < 4; i++)
#pragma unroll
        for (int j = 0; j < 4; j++)
          acc[i][j] = __builtin_amdgcn_mfma_f32_16x16x32_bf16(af[i], bfr[j], acc[i][j], 0, 0, 0);
    }
  }
  // epilogue: D row = quad*4+reg, col = lane&15 (per 16x16 fragment)
#pragma unroll
  for (int j = 0; j < 4; j++) {
    int col = n0 + wc * 64 + j * 16 + l15;
    float bv = bias[col];
#pragma unroll
    for (int i = 0; i < 4; i++) {
      int rbase = m0 + wr * 64 + i * 16 + quad * 4;
#pragma unroll
      for (int reg = 0; reg < 4; reg++) {
        int r = rbase + reg;
        if (r < M) {
          float o = acc[i][j][reg] + bv;
          if (relu) o = fmaxf(o, 0.f);
          Cc[(size_t)r * ldc + col] = f2b(o);
        }
      }
    }
  }
}

// ---------------- pooling: gather-reduce, one wave per segment ----------------
// PCb[seg, coloff + 0:256] = mean over nodes in segment of h[node, 0:256]

__global__ void pool_gather_kernel(const u16* __restrict__ h,
                                   const int* __restrict__ offp, const int* __restrict__ cntp,
                                   const int* __restrict__ pcsr,
                                   u16* __restrict__ PCb, int coloff) {
  int w = (blockIdx.x * blockDim.x + threadIdx.x) >> 6;
  int lane = threadIdx.x & 63;
  if (w >= S) return;
  int st = offp[w];
  int ct = cntp[w];
  float4 acc = make_float4(0.f, 0.f, 0.f, 0.f);
  for (int e = 0; e < ct; e++) {
    int node = pcsr[st + e];
    ushort4 v = ((const ushort4*)(h + (size_t)node * 256))[lane];
    acc.x += b2f(v.x); acc.y += b2f(v.y); acc.z += b2f(v.z); acc.w += b2f(v.w);
  }
  float inv = 1.0f / fmaxf((float)ct, 1.0f);
  ushort4 o;
  o.x = f2b(acc.x * inv); o.y = f2b(acc.y * inv);
  o.z = f2b(acc.z * inv); o.w = f2b(acc.w * inv);
  ((ushort4*)(PCb + (size_t)w * 512 + coloff))[lane] = o;
}

// ---------------- classifier head: logits (256->7) + log_softmax ----------------

__global__ void final_kernel(const u16* __restrict__ PH, const float* __restrict__ w2,
                             const float* __restrict__ b2, float* __restrict__ out) {
  int wv = (blockIdx.x * blockDim.x + threadIdx.x) >> 6;
  int lane = threadIdx.x & 63;
  if (wv >= S) return;
  ushort4 hv = ((const ushort4*)(PH + (size_t)wv * 256))[lane];
  float hx = b2f(hv.x), hy = b2f(hv.y), hz = b2f(hv.z), hw = b2f(hv.w);
  int k = lane * 4;
  float lg[C];
#pragma unroll
  for (int c = 0; c < C; c++) {
    float p = hx * w2[(k + 0) * C + c] + hy * w2[(k + 1) * C + c] +
              hz * w2[(k + 2) * C + c] + hw * w2[(k + 3) * C + c];
#pragma unroll
    for (int o = 32; o > 0; o >>= 1) p += __shfl_down(p, o);
    lg[c] = p;
  }
  if (lane == 0) {
    float mx = -1e30f;
#pragma unroll
    for (int c = 0; c < C; c++) { lg[c] += b2[c]; mx = fmaxf(mx, lg[c]); }
    float ssum = 0.f;
#pragma unroll
    for (int c = 0; c < C; c++) ssum += expf(lg[c] - mx);
    float ls = logf(ssum);
#pragma unroll
    for (int c = 0; c < C; c++) out[(size_t)wv * C + c] = lg[c] - mx - ls;
  }
}

} // anonymous namespace

extern "C" void kernel_launch(void* const* d_in, const int* in_sizes, int n_in,
                              void* d_out, int out_size, void* d_ws, size_t ws_size,
                              hipStream_t stream) {
  const float* x    = (const float*)d_in[0];
  const int*   ei1  = (const int*)d_in[1];
  const int*   ei2  = (const int*)d_in[2];
  const int*   idx1 = (const int*)d_in[3];
  const int*   idx2 = (const int*)d_in[4];
  const float* w11 = (const float*)d_in[5];  const float* b11 = (const float*)d_in[6];
  const float* w12 = (const float*)d_in[7];  const float* b12 = (const float*)d_in[8];
  const float* w21 = (const float*)d_in[9];  const float* b21 = (const float*)d_in[10];
  const float* w22 = (const float*)d_in[11]; const float* b22 = (const float*)d_in[12];
  const float* m1w1 = (const float*)d_in[13]; const float* m1b1 = (const float*)d_in[14];
  const float* m1w2 = (const float*)d_in[15]; const float* m1b2 = (const float*)d_in[16];
  const float* m2w1 = (const float*)d_in[17]; const float* m2b1 = (const float*)d_in[18];
  const float* m2w2 = (const float*)d_in[19]; const float* m2b2 = (const float*)d_in[20];
  const float* mw1 = (const float*)d_in[21]; const float* mb1 = (const float*)d_in[22];
  const float* mw2 = (const float*)d_in[23]; const float* mb2 = (const float*)d_in[24];
  float* out = (float*)d_out;
  (void)n_in; (void)in_sizes; (void)out_size;

  // ---- workspace carve-up ----
  char* base = (char*)d_ws;
  size_t p = 0;
  auto alloc = [&](size_t bytes) {
    void* r = base + p;
    p += (bytes + 255) & ~(size_t)255;
    return r;
  };
  u16* B1 = (u16*)alloc((size_t)N * 256 * 2);
  u16* B2 = (u16*)alloc((size_t)N * 256 * 2);
  u16* B3 = (u16*)alloc((size_t)N * 256 * 2);
  float* dis1 = (float*)alloc((size_t)N * 4);
  float* dis2 = (float*)alloc((size_t)N * 4);
  int* cnt1 = (int*)alloc((size_t)N * 4);
  int* cnt2 = (int*)alloc((size_t)N * 4);
  int* off1 = (int*)alloc((size_t)N * 4);
  int* off2 = (int*)alloc((size_t)N * 4);
  int* cur1 = (int*)alloc((size_t)N * 4);
  int* cur2 = (int*)alloc((size_t)N * 4);
  int* csr1 = (int*)alloc((size_t)E * 4);
  int* csr2 = (int*)alloc((size_t)E * 4);
  int* bsum = (int*)alloc(256);
  // pooling CSR
  int* cntp1 = (int*)alloc((size_t)S * 4);
  int* cntp2 = (int*)alloc((size_t)S * 4);
  int* offp1 = (int*)alloc((size_t)S * 4);
  int* offp2 = (int*)alloc((size_t)S * 4);
  int* curp1 = (int*)alloc((size_t)S * 4);
  int* curp2 = (int*)alloc((size_t)S * 4);
  int* pcsr1 = (int*)alloc((size_t)N * 4);
  int* pcsr2 = (int*)alloc((size_t)N * 4);
  u16* PCb = (u16*)alloc((size_t)S * 512 * 2);
  u16* PH  = (u16*)alloc((size_t)S * 256 * 2);
  // transposed bf16 weights
  u16* w11t  = (u16*)alloc((size_t)256 * 128 * 2);
  u16* w12t  = (u16*)alloc((size_t)256 * 128 * 2);
  u16* m1w1t = (u16*)alloc((size_t)256 * 512 * 2);
  u16* m1w2t = (u16*)alloc((size_t)256 * 256 * 2);
  u16* w21t  = (u16*)alloc((size_t)256 * 256 * 2);
  u16* w22t  = (u16*)alloc((size_t)256 * 256 * 2);
  u16* m2w1t = (u16*)alloc((size_t)256 * 512 * 2);
  u16* m2w2t = (u16*)alloc((size_t)256 * 256 * 2);
  u16* mw1t  = (u16*)alloc((size_t)256 * 512 * 2);
  size_t p_base = p;
  u16* xb = (u16*)alloc((size_t)N * 128 * 2);   // bf16 copy of x (optional)
  bool use_xb = (p <= ws_size);
  if (p_base > ws_size) return; // ws too small: fail cleanly, not a fault

  constexpr int NB_N = (N + SCAN_CH - 1) / SCAN_CH; // 49
  constexpr int NB_S = (S + SCAN_CH - 1) / SCAN_CH; // 3

  auto build_csr = [&](const int* ei, int* cnt, int* off, int* cur, int* csr, float* dis) {
    const int* row = ei;
    const int* col = ei + E;
    hipMemsetAsync(cnt, 0, N * sizeof(int), stream);
    hipLaunchKernelGGL(hist_kernel, dim3((E + 255) / 256), dim3(256), 0, stream, col, cnt, E);
    hipLaunchKernelGGL(dis_kernel, dim3((N + 255) / 256), dim3(256), 0, stream, cnt, dis);
    hipLaunchKernelGGL(scan_sum_kernel, dim3(NB_N), dim3(256), 0, stream, cnt, bsum, N);
    hipLaunchKernelGGL(scan_bsum_kernel, dim3(1), dim3(1), 0, stream, bsum, NB_N);
    hipLaunchKernelGGL(scan_final_kernel, dim3(NB_N), dim3(256), 0, stream, cnt, bsum, off, cur, N);
    hipLaunchKernelGGL(csr_scatter_kernel, dim3((E + 255) / 256), dim3(256), 0, stream,
                       row, col, cur, csr);
  };

  auto build_pool_csr = [&](const int* idx, int* cnt, int* off, int* cur, int* pcsr) {
    hipMemsetAsync(cnt, 0, S * sizeof(int), stream);
    hipLaunchKernelGGL(hist_kernel, dim3((N + 255) / 256), dim3(256), 0, stream, idx, cnt, N);
    hipLaunchKernelGGL(scan_sum_kernel, dim3(NB_S), dim3(256), 0, stream, cnt, bsum, S);
    hipLaunchKernelGGL(scan_bsum_kernel, dim3(1), dim3(1), 0, stream, bsum, NB_S);
    hipLaunchKernelGGL(scan_final_kernel, dim3(NB_S), dim3(256), 0, stream, cnt, bsum, off, cur, S);
    hipLaunchKernelGGL(pool_scatter_kernel, dim3((N + 255) / 256), dim3(256), 0, stream,
                       idx, cur, pcsr);
  };

  auto wtrans = [&](const float* W, u16* Wt, int K) {
    hipLaunchKernelGGL(wt_kernel, dim3(K), dim3(256), 0, stream, W, Wt, K);
  };

  auto gemm = [&](const u16* A1, int lda1, int K1, const u16* A2, int lda2, int K2,
                  const u16* Wt, const float* bias, u16* Cc, int M, int relu) {
    hipLaunchKernelGGL(mfma_gemm_kernel, dim3(2, (M + 127) / 128), dim3(256), 0, stream,
                       A1, lda1, K1, A2, lda2, K2, Wt, bias, Cc, 256, M, relu);
  };

  // ---- weight transposes (tiny) ----
  wtrans(w11, w11t, 128);
  wtrans(w12, w12t, 128);
  wtrans(m1w1, m1w1t, 512);
  wtrans(m1w2, m1w2t, 256);
  wtrans(w21, w21t, 256);
  wtrans(w22, w22t, 256);
  wtrans(m2w1, m2w1t, 512);
  wtrans(m2w2, m2w2t, 256);
  wtrans(mw1, mw1t, 512);

  // ---- CSR for both edge lists and both pooling indices ----
  build_csr(ei1, cnt1, off1, cur1, csr1, dis1);
  build_csr(ei2, cnt2, off2, cur2, csr2, dis2);
  build_pool_csr(idx1, cntp1, offp1, curp1, pcsr1);
  build_pool_csr(idx2, cntp2, offp2, curp2, pcsr2);

  // ---- layer 1: conv = agg-then-GEMM (A@(XW) == (A@X)@W) ----
  if (use_xb) {
    hipLaunchKernelGGL(f32_to_b16_kernel, dim3((N * 128 / 4 + 255) / 256), dim3(256), 0, stream,
                       x, xb, N * 128 / 4);
    hipLaunchKernelGGL(agg_b16_kernel, dim3(N / 4), dim3(256), 0, stream,
                       xb, 128, B3, 128, off1, cnt1, csr1, dis1, 32);
  } else {
    hipLaunchKernelGGL(agg_f32_kernel, dim3(N / 4), dim3(256), 0, stream,
                       x, 128, B3, 128, off1, cnt1, csr1, dis1, 32);
  }
  gemm(B3, 128, 128, nullptr, 0, 0, w11t, b11, B1, N, 1);        // x1 -> B1
  if (use_xb) {
    hipLaunchKernelGGL(agg_b16_kernel, dim3(N / 4), dim3(256), 0, stream,
                       xb, 128, B3, 128, off2, cnt2, csr2, dis2, 32);
  } else {
    hipLaunchKernelGGL(agg_f32_kernel, dim3(N / 4), dim3(256), 0, stream,
                       x, 128, B3, 128, off2, cnt2, csr2, dis2, 32);
  }
  gemm(B3, 128, 128, nullptr, 0, 0, w12t, b12, B2, N, 1);        // x2 -> B2
  // mlp_1
  gemm(B1, 256, 256, B2, 256, 256, m1w1t, m1b1, B3, N, 1);       // Hm -> B3
  gemm(B3, 256, 256, nullptr, 0, 0, m1w2t, m1b2, B1, N, 0);      // h  -> B1

  // ---- layer 2 ----
  hipLaunchKernelGGL(agg_b16_kernel, dim3(N / 4), dim3(256), 0, stream,
                     B1, 256, B2, 256, off1, cnt1, csr1, dis1, 64);
  gemm(B2, 256, 256, nullptr, 0, 0, w21t, b21, B3, N, 1);        // y1 -> B3
  hipLaunchKernelGGL(agg_b16_kernel, dim3(N / 4), dim3(256), 0, stream,
                     B1, 256, B2, 256, off2, cnt2, csr2, dis2, 64);
  gemm(B2, 256, 256, nullptr, 0, 0, w22t, b22, B1, N, 1);        // y2 -> B1
  // mlp_2
  gemm(B3, 256, 256, B1, 256, 256, m2w1t, m2b1, B2, N, 1);       // Hm2 -> B2
  gemm(B2, 256, 256, nullptr, 0, 0, m2w2t, m2b2, B3, N, 0);      // h2 -> B3

  // ---- pooling: deterministic gather-reduce (no atomics on features) ----
  hipLaunchKernelGGL(pool_gather_kernel, dim3((S + 3) / 4), dim3(256), 0, stream,
                     B3, offp1, cntp1, pcsr1, PCb, 0);
  hipLaunchKernelGGL(pool_gather_kernel, dim3((S + 3) / 4), dim3(256), 0, stream,
                     B3, offp2, cntp2, pcsr2, PCb, 256);

  // ---- classifier head ----
  gemm(PCb, 512, 512, nullptr, 0, 0, mw1t, mb1, PH, S, 1);
  hipLaunchKernelGGL(final_kernel, dim3((S + 3) / 4), dim3(256), 0, stream,
                     PH, mw2, mb2, out);
}

// Round 5
// 1009.169 us; speedup vs baseline: 2.9027x; 1.2632x over previous
//
#include <hip/hip_runtime.h>
#include <math.h>

namespace {

constexpr int N = 100000;
constexpr int E = 800000;
constexpr int S = 5000;
constexpr int C = 7;
constexpr int SCAN_CH = 2048;

typedef unsigned short u16;
typedef short bf16x8 __attribute__((ext_vector_type(8)));
typedef float f32x4 __attribute__((ext_vector_type(4)));

__device__ __forceinline__ float b2f(u16 u) {
  return __uint_as_float(((unsigned int)u) << 16);
}
__device__ __forceinline__ u16 f2b(float f) {
  unsigned int u = __float_as_uint(f);
  return (u16)((u + 0x7fffu + ((u >> 16) & 1u)) >> 16); // RNE
}

__device__ __forceinline__ void gl2lds16(const void* g, void* l) {
  __builtin_amdgcn_global_load_lds(
      (const __attribute__((address_space(1))) unsigned int*)g,
      (__attribute__((address_space(3))) unsigned int*)l, 16, 0, 0);
}

// ---------------- batched histogram / scan / scatter (CSR build) ----------------
// blockIdx.y in {0,1} selects dataset A/B.

__global__ void hist2_kernel(const int* __restrict__ colA, int* __restrict__ cntA,
                             const int* __restrict__ colB, int* __restrict__ cntB, int n) {
  const int* col = blockIdx.y ? colB : colA;
  int* cnt = blockIdx.y ? cntB : cntA;
  int e = blockIdx.x * blockDim.x + threadIdx.x;
  if (e < n) atomicAdd(&cnt[col[e]], 1);
}

__global__ void dis2_kernel(const int* __restrict__ cntA, float* __restrict__ disA,
                            const int* __restrict__ cntB, float* __restrict__ disB) {
  const int* cnt = blockIdx.y ? cntB : cntA;
  float* dis = blockIdx.y ? disB : disA;
  int i = blockIdx.x * blockDim.x + threadIdx.x;
  if (i < N) dis[i] = rsqrtf((float)cnt[i] + 1.0f); // +1 self loop
}

__global__ void scan_sum2_kernel(const int* __restrict__ cntA, const int* __restrict__ cntB,
                                 int* __restrict__ bsum, int n) {
  const int* cnt = blockIdx.y ? cntB : cntA;
  int* bs = bsum + blockIdx.y * 128;
  __shared__ int sh[256];
  int base = blockIdx.x * SCAN_CH;
  int s = 0;
  for (int i = threadIdx.x; i < SCAN_CH; i += 256) {
    int g = base + i;
    s += (g < n) ? cnt[g] : 0;
  }
  sh[threadIdx.x] = s;
  __syncthreads();
  for (int o = 128; o > 0; o >>= 1) {
    if (threadIdx.x < o) sh[threadIdx.x] += sh[threadIdx.x + o];
    __syncthreads();
  }
  if (threadIdx.x == 0) bs[blockIdx.x] = sh[0];
}

__global__ void scan_bsum2_kernel(int* __restrict__ bsum, int nb) {
  if (threadIdx.x == 0 && blockIdx.x == 0) {
    for (int b = 0; b < 2; b++) {
      int* bs = bsum + b * 128;
      int acc = 0;
      for (int i = 0; i < nb; i++) { int v = bs[i]; bs[i] = acc; acc += v; }
    }
  }
}

__global__ void scan_final2_kernel(const int* __restrict__ cntA, int* __restrict__ offA,
                                   int* __restrict__ curA,
                                   const int* __restrict__ cntB, int* __restrict__ offB,
                                   int* __restrict__ curB,
                                   const int* __restrict__ bsum, int n) {
  const int* cnt = blockIdx.y ? cntB : cntA;
  int* off = blockIdx.y ? offB : offA;
  int* cur = blockIdx.y ? curB : curA;
  const int* bs = bsum + blockIdx.y * 128;
  __shared__ int sh[256];
  int t = threadIdx.x;
  int base = blockIdx.x * SCAN_CH + t * 8;
  int loc[8];
  int s = 0;
#pragma unroll
  for (int j = 0; j < 8; j++) {
    int g = base + j;
    loc[j] = s;
    s += (g < n) ? cnt[g] : 0;
  }
  sh[t] = s;
  __syncthreads();
  for (int o = 1; o < 256; o <<= 1) {
    int v = (t >= o) ? sh[t - o] : 0;
    __syncthreads();
    sh[t] += v;
    __syncthreads();
  }
  int pre = bs[blockIdx.x] + ((t > 0) ? sh[t - 1] : 0);
#pragma unroll
  for (int j = 0; j < 8; j++) {
    int g = base + j;
    if (g < n) { int v = pre + loc[j]; off[g] = v; cur[g] = v; }
  }
}

__global__ void csr_scatter2_kernel(const int* __restrict__ eiA, int* __restrict__ curA,
                                    int* __restrict__ csrA,
                                    const int* __restrict__ eiB, int* __restrict__ curB,
                                    int* __restrict__ csrB) {
  const int* ei = blockIdx.y ? eiB : eiA;
  int* cur = blockIdx.y ? curB : curA;
  int* csr = blockIdx.y ? csrB : csrA;
  const int* row = ei;
  const int* col = ei + E;
  int e = blockIdx.x * blockDim.x + threadIdx.x;
  if (e < E) {
    int c = col[e];
    int slot = atomicAdd(&cur[c], 1);
    csr[slot] = row[e];
  }
}

__global__ void pool_scatter2_kernel(const int* __restrict__ idxA, int* __restrict__ curA,
                                     int* __restrict__ pcsrA,
                                     const int* __restrict__ idxB, int* __restrict__ curB,
                                     int* __restrict__ pcsrB) {
  const int* idx = blockIdx.y ? idxB : idxA;
  int* cur = blockIdx.y ? curB : curA;
  int* pcsr = blockIdx.y ? pcsrB : pcsrA;
  int i = blockIdx.x * blockDim.x + threadIdx.x;
  if (i < N) {
    int s = idx[i];
    int slot = atomicAdd(&cur[s], 1);
    pcsr[slot] = i;
  }
}

// ---------------- converts ----------------

__global__ void f32_to_b16_kernel(const float* __restrict__ in, u16* __restrict__ out, int n4) {
  int t = blockIdx.x * blockDim.x + threadIdx.x;
  if (t >= n4) return;
  float4 v = ((const float4*)in)[t];
  ushort4 o;
  o.x = f2b(v.x); o.y = f2b(v.y); o.z = f2b(v.z); o.w = f2b(v.w);
  ((ushort4*)out)[t] = o;
}

// batched weight transpose+convert: W fp32 [K x 256] -> Wt bf16 [256 x K]
struct WtJobs {
  const float* W[9];
  u16* Wt[9];
  int K[9];
  int boff[10]; // cumulative blocks (K per job)
};

__global__ void wt_batch_kernel(WtJobs jobs) {
  int blk = blockIdx.x;
  int j = 0;
  while (blk >= jobs.boff[j + 1]) j++;
  int t = (blk - jobs.boff[j]) * 256 + threadIdx.x;
  int K = jobs.K[j];
  int k = t >> 8;
  int n = t & 255;
  jobs.Wt[j][(size_t)n * K + k] = f2b(jobs.W[j][t]);
}

// ---------------- aggregation ----------------
// out[i] = dis[i]*(sum_j dis[j]*in[j] + dis[i]*in[i])
// DV = active lanes per node row (ushort4 each); 64/DV nodes per wave.
// blockIdx.y selects graph (A/B) with its own CSR and output.

template <int DV>
__global__ void agg2_kernel(const u16* __restrict__ in, int ldin,
                            u16* __restrict__ outA, u16* __restrict__ outB,
                            const int* __restrict__ offA, const int* __restrict__ cntA,
                            const int* __restrict__ csrA, const float* __restrict__ disA,
                            const int* __restrict__ offB, const int* __restrict__ cntB,
                            const int* __restrict__ csrB, const float* __restrict__ disB) {
  const int* off; const int* cnt; const int* csr; const float* dis; u16* out;
  if (blockIdx.y == 0) { off = offA; cnt = cntA; csr = csrA; dis = disA; out = outA; }
  else                 { off = offB; cnt = cntB; csr = csrB; dis = disB; out = outB; }
  constexpr int NPW = 64 / DV;
  int wv = (blockIdx.x * blockDim.x + threadIdx.x) >> 6;
  int lane = threadIdx.x & 63;
  int sub = lane / DV;
  int sl = lane % DV;
  int node = wv * NPW + sub;
  if (node >= N) return;
  float di = dis[node];
  int st = off[node];
  int ct = cnt[node];
  ushort4 sv = ((const ushort4*)(in + (size_t)node * ldin))[sl];
  float4 a0, a1, a2, a3;
  a0 = make_float4(di * b2f(sv.x), di * b2f(sv.y), di * b2f(sv.z), di * b2f(sv.w));
  a1 = make_float4(0.f, 0.f, 0.f, 0.f);
  a2 = a1; a3 = a1;
  int e = 0;
  for (; e + 4 <= ct; e += 4) {
    int s0 = csr[st + e + 0], s1 = csr[st + e + 1];
    int s2 = csr[st + e + 2], s3 = csr[st + e + 3];
    float d0 = dis[s0], d1 = dis[s1], d2 = dis[s2], d3 = dis[s3];
    ushort4 v0 = ((const ushort4*)(in + (size_t)s0 * ldin))[sl];
    ushort4 v1 = ((const ushort4*)(in + (size_t)s1 * ldin))[sl];
    ushort4 v2 = ((const ushort4*)(in + (size_t)s2 * ldin))[sl];
    ushort4 v3 = ((const ushort4*)(in + (size_t)s3 * ldin))[sl];
    a0.x += d0 * b2f(v0.x); a0.y += d0 * b2f(v0.y); a0.z += d0 * b2f(v0.z); a0.w += d0 * b2f(v0.w);
    a1.x += d1 * b2f(v1.x); a1.y += d1 * b2f(v1.y); a1.z += d1 * b2f(v1.z); a1.w += d1 * b2f(v1.w);
    a2.x += d2 * b2f(v2.x); a2.y += d2 * b2f(v2.y); a2.z += d2 * b2f(v2.z); a2.w += d2 * b2f(v2.w);
    a3.x += d3 * b2f(v3.x); a3.y += d3 * b2f(v3.y); a3.z += d3 * b2f(v3.z); a3.w += d3 * b2f(v3.w);
  }
  for (; e < ct; e++) {
    int s0 = csr[st + e];
    float d0 = dis[s0];
    ushort4 v0 = ((const ushort4*)(in + (size_t)s0 * ldin))[sl];
    a0.x += d0 * b2f(v0.x); a0.y += d0 * b2f(v0.y); a0.z += d0 * b2f(v0.z); a0.w += d0 * b2f(v0.w);
  }
  float4 acc;
  acc.x = (a0.x + a1.x) + (a2.x + a3.x);
  acc.y = (a0.y + a1.y) + (a2.y + a3.y);
  acc.z = (a0.z + a1.z) + (a2.z + a3.z);
  acc.w = (a0.w + a1.w) + (a2.w + a3.w);
  ushort4 o;
  o.x = f2b(di * acc.x); o.y = f2b(di * acc.y);
  o.z = f2b(di * acc.z); o.w = f2b(di * acc.w);
  ((ushort4*)(out + (size_t)node * ldin))[sl] = o;
}

// fp32-input fallback (only used if ws too small for xb)
__global__ void agg_f32_kernel(const float* __restrict__ in, int ldin,
                               u16* __restrict__ out, int ldout,
                               const int* __restrict__ off, const int* __restrict__ cnt,
                               const int* __restrict__ csr, const float* __restrict__ dis,
                               int dv) {
  int w = (blockIdx.x * blockDim.x + threadIdx.x) >> 6;
  int lane = threadIdx.x & 63;
  if (w >= N || lane >= dv) return;
  float di = dis[w];
  int st = off[w];
  int ct = cnt[w];
  float4 acc = ((const float4*)(in + (size_t)w * ldin))[lane];
  acc.x *= di; acc.y *= di; acc.z *= di; acc.w *= di;
  for (int e = 0; e < ct; e++) {
    int sidx = csr[st + e];
    float ds = dis[sidx];
    float4 v = ((const float4*)(in + (size_t)sidx * ldin))[lane];
    acc.x += ds * v.x; acc.y += ds * v.y; acc.z += ds * v.z; acc.w += ds * v.w;
  }
  ushort4 o;
  o.x = f2b(di * acc.x); o.y = f2b(di * acc.y);
  o.z = f2b(di * acc.z); o.w = f2b(di * acc.w);
  ((ushort4*)(out + (size_t)w * ldout))[lane] = o;
}

// ---------------- MFMA GEMM: C = act([A1|A2] @ W + bias), W as Wt[256][Ktot] ----
// 128x128 tile, 4 waves (2x2), each wave 64x64 via 4x4 mfma_f32_16x16x32_bf16.
// Staging via global_load_lds width=16 with XOR column-group swizzle on the
// SOURCE address (g ^ (row&7)): LDS stays contiguous (required by the DMA),
// global reads stay coalesced (permutation within 128B segment), and the
// fragment ds_read_b128s are conflict-free (2 lanes per 4-bank group).
// OOB M rows read garbage (inside ws) but are masked at store.

__global__ __launch_bounds__(256, 3) void mfma_gemm_kernel(
    const u16* __restrict__ A1, int lda1, int K1,
    const u16* __restrict__ A2, int lda2, int K2,
    const u16* __restrict__ Wt,
    const float* __restrict__ bias,
    u16* __restrict__ Cc, int ldc, int M, int relu) {
  __shared__ __align__(16) u16 As[128 * 64];
  __shared__ __align__(16) u16 Bs[128 * 64];
  int tid = threadIdx.x;
  int lane = tid & 63;
  int wid = tid >> 6;
  int wr = wid >> 1, wc = wid & 1;
  int quad = lane >> 4;
  int l15 = lane & 15;
  int lrow = lane >> 3; // 0..7 within 8-row chunk
  int lg = lane & 7;    // col group 0..7
  int m0 = blockIdx.y * 128;
  int n0 = blockIdx.x * 128;
  int Ktot = K1 + K2;
  f32x4 acc[4][4];
#pragma unroll
  for (int i = 0; i < 4; i++)
#pragma unroll
    for (int j = 0; j < 4; j++)
      acc[i][j] = (f32x4){0.f, 0.f, 0.f, 0.f};
  for (int k0 = 0; k0 < Ktot; k0 += 64) {
    const u16* A; int lda; int kloc;
    if (k0 < K1) { A = A1; lda = lda1; kloc = k0; }
    else         { A = A2; lda = lda2; kloc = k0 - K1; }
    __syncthreads(); // previous tile fully consumed before overwrite
#pragma unroll
    for (int j = 0; j < 4; j++) {
      int chunk = wid * 4 + j;        // 0..15 (8 rows each)
      int row = chunk * 8 + lrow;     // 0..127
      int gcol = (lg ^ (row & 7)) * 8;
      gl2lds16(A + (size_t)(m0 + row) * lda + kloc + gcol, &As[chunk * 512]);
      gl2lds16(Wt + (size_t)(n0 + row) * Ktot + k0 + gcol, &Bs[chunk * 512]);
    }
    __syncthreads();
#pragma unroll
    for (int kk = 0; kk < 2; kk++) {
      bf16x8 af[4], bfr[4];
#pragma unroll
      for (int i = 0; i < 4; i++) {
        int ra = wr * 64 + i * 16 + l15;
        int ga = ((kk * 4 + quad) ^ (ra & 7)) * 8;
        af[i] = *(const bf16x8*)&As[ra * 64 + ga];
        int rb = wc * 64 + i * 16 + l15;
        int gb = ((kk * 4 + quad) ^ (rb & 7)) * 8;
        bfr[i] = *(const bf16x8*)&Bs[rb * 64 + gb];
      }
#pragma unroll
      for (int i = 0; i < 4; i++)
#pragma unroll
        for (int j = 0; j < 4; j++)
          acc[i][j] = __builtin_amdgcn_mfma_f32_16x16x32_bf16(af[i], bfr[j], acc[i][j], 0, 0, 0);
    }
  }
  // epilogue: D row = quad*4+reg, col = lane&15 (per 16x16 fragment)
#pragma unroll
  for (int j = 0; j < 4; j++) {
    int col = n0 + wc * 64 + j * 16 + l15;
    float bv = bias[col];
#pragma unroll
    for (int i = 0; i < 4; i++) {
      int rbase = m0 + wr * 64 + i * 16 + quad * 4;
#pragma unroll
      for (int reg = 0; reg < 4; reg++) {
        int r = rbase + reg;
        if (r < M) {
          float o = acc[i][j][reg] + bv;
          if (relu) o = fmaxf(o, 0.f);
          Cc[(size_t)r * ldc + col] = f2b(o);
        }
      }
    }
  }
}

// ---------------- pooling: gather-reduce, one wave per segment, both sets ----

__global__ void pool_gather2_kernel(const u16* __restrict__ h,
                                    const int* __restrict__ offA, const int* __restrict__ cntA,
                                    const int* __restrict__ pcsrA,
                                    const int* __restrict__ offB, const int* __restrict__ cntB,
                                    const int* __restrict__ pcsrB,
                                    u16* __restrict__ PCb) {
  const int* offp; const int* cntp; const int* pcsr; int coloff;
  if (blockIdx.y == 0) { offp = offA; cntp = cntA; pcsr = pcsrA; coloff = 0; }
  else                 { offp = offB; cntp = cntB; pcsr = pcsrB; coloff = 256; }
  int w = (blockIdx.x * blockDim.x + threadIdx.x) >> 6;
  int lane = threadIdx.x & 63;
  if (w >= S) return;
  int st = offp[w];
  int ct = cntp[w];
  float4 a0 = make_float4(0.f, 0.f, 0.f, 0.f);
  float4 a1 = a0, a2 = a0, a3 = a0;
  int e = 0;
  for (; e + 4 <= ct; e += 4) {
    int n0 = pcsr[st + e + 0], n1 = pcsr[st + e + 1];
    int n2 = pcsr[st + e + 2], n3 = pcsr[st + e + 3];
    ushort4 v0 = ((const ushort4*)(h + (size_t)n0 * 256))[lane];
    ushort4 v1 = ((const ushort4*)(h + (size_t)n1 * 256))[lane];
    ushort4 v2 = ((const ushort4*)(h + (size_t)n2 * 256))[lane];
    ushort4 v3 = ((const ushort4*)(h + (size_t)n3 * 256))[lane];
    a0.x += b2f(v0.x); a0.y += b2f(v0.y); a0.z += b2f(v0.z); a0.w += b2f(v0.w);
    a1.x += b2f(v1.x); a1.y += b2f(v1.y); a1.z += b2f(v1.z); a1.w += b2f(v1.w);
    a2.x += b2f(v2.x); a2.y += b2f(v2.y); a2.z += b2f(v2.z); a2.w += b2f(v2.w);
    a3.x += b2f(v3.x); a3.y += b2f(v3.y); a3.z += b2f(v3.z); a3.w += b2f(v3.w);
  }
  for (; e < ct; e++) {
    int n0 = pcsr[st + e];
    ushort4 v0 = ((const ushort4*)(h + (size_t)n0 * 256))[lane];
    a0.x += b2f(v0.x); a0.y += b2f(v0.y); a0.z += b2f(v0.z); a0.w += b2f(v0.w);
  }
  float inv = 1.0f / fmaxf((float)ct, 1.0f);
  ushort4 o;
  o.x = f2b(((a0.x + a1.x) + (a2.x + a3.x)) * inv);
  o.y = f2b(((a0.y + a1.y) + (a2.y + a3.y)) * inv);
  o.z = f2b(((a0.z + a1.z) + (a2.z + a3.z)) * inv);
  o.w = f2b(((a0.w + a1.w) + (a2.w + a3.w)) * inv);
  ((ushort4*)(PCb + (size_t)w * 512 + coloff))[lane] = o;
}

// ---------------- classifier head: logits (256->7) + log_softmax ----------------

__global__ void final_kernel(const u16* __restrict__ PH, const float* __restrict__ w2,
                             const float* __restrict__ b2, float* __restrict__ out) {
  int wv = (blockIdx.x * blockDim.x + threadIdx.x) >> 6;
  int lane = threadIdx.x & 63;
  if (wv >= S) return;
  ushort4 hv = ((const ushort4*)(PH + (size_t)wv * 256))[lane];
  float hx = b2f(hv.x), hy = b2f(hv.y), hz = b2f(hv.z), hw = b2f(hv.w);
  int k = lane * 4;
  float lg[C];
#pragma unroll
  for (int c = 0; c < C; c++) {
    float p = hx * w2[(k + 0) * C + c] + hy * w2[(k + 1) * C + c] +
              hz * w2[(k + 2) * C + c] + hw * w2[(k + 3) * C + c];
#pragma unroll
    for (int o = 32; o > 0; o >>= 1) p += __shfl_down(p, o);
    lg[c] = p;
  }
  if (lane == 0) {
    float mx = -1e30f;
#pragma unroll
    for (int c = 0; c < C; c++) { lg[c] += b2[c]; mx = fmaxf(mx, lg[c]); }
    float ssum = 0.f;
#pragma unroll
    for (int c = 0; c < C; c++) ssum += expf(lg[c] - mx);
    float ls = logf(ssum);
#pragma unroll
    for (int c = 0; c < C; c++) out[(size_t)wv * C + c] = lg[c] - mx - ls;
  }
}

} // anonymous namespace

extern "C" void kernel_launch(void* const* d_in, const int* in_sizes, int n_in,
                              void* d_out, int out_size, void* d_ws, size_t ws_size,
                              hipStream_t stream) {
  const float* x    = (const float*)d_in[0];
  const int*   ei1  = (const int*)d_in[1];
  const int*   ei2  = (const int*)d_in[2];
  const int*   idx1 = (const int*)d_in[3];
  const int*   idx2 = (const int*)d_in[4];
  const float* w11 = (const float*)d_in[5];  const float* b11 = (const float*)d_in[6];
  const float* w12 = (const float*)d_in[7];  const float* b12 = (const float*)d_in[8];
  const float* w21 = (const float*)d_in[9];  const float* b21 = (const float*)d_in[10];
  const float* w22 = (const float*)d_in[11]; const float* b22 = (const float*)d_in[12];
  const float* m1w1 = (const float*)d_in[13]; const float* m1b1 = (const float*)d_in[14];
  const float* m1w2 = (const float*)d_in[15]; const float* m1b2 = (const float*)d_in[16];
  const float* m2w1 = (const float*)d_in[17]; const float* m2b1 = (const float*)d_in[18];
  const float* m2w2 = (const float*)d_in[19]; const float* m2b2 = (const float*)d_in[20];
  const float* mw1 = (const float*)d_in[21]; const float* mb1 = (const float*)d_in[22];
  const float* mw2 = (const float*)d_in[23]; const float* mb2 = (const float*)d_in[24];
  float* out = (float*)d_out;
  (void)n_in; (void)in_sizes; (void)out_size;

  // ---- workspace carve-up ----
  char* base = (char*)d_ws;
  size_t p = 0;
  auto alloc = [&](size_t bytes) {
    void* r = base + p;
    p += (bytes + 255) & ~(size_t)255;
    return r;
  };
  u16* B1 = (u16*)alloc((size_t)N * 256 * 2);
  u16* B2 = (u16*)alloc((size_t)N * 256 * 2);
  u16* B3 = (u16*)alloc((size_t)N * 256 * 2);
  float* dis1 = (float*)alloc((size_t)N * 4);
  float* dis2 = (float*)alloc((size_t)N * 4);
  int* cntE = (int*)alloc((size_t)2 * N * 4);  // cnt1|cnt2 contiguous
  int* cnt1 = cntE;
  int* cnt2 = cntE + N;
  int* off1 = (int*)alloc((size_t)N * 4);
  int* off2 = (int*)alloc((size_t)N * 4);
  int* cur1 = (int*)alloc((size_t)N * 4);
  int* cur2 = (int*)alloc((size_t)N * 4);
  int* csr1 = (int*)alloc((size_t)E * 4);
  int* csr2 = (int*)alloc((size_t)E * 4);
  int* bsum = (int*)alloc(1024);
  // pooling CSR
  int* cntP = (int*)alloc((size_t)2 * S * 4);  // cntp1|cntp2 contiguous
  int* cntp1 = cntP;
  int* cntp2 = cntP + S;
  int* offp1 = (int*)alloc((size_t)S * 4);
  int* offp2 = (int*)alloc((size_t)S * 4);
  int* curp1 = (int*)alloc((size_t)S * 4);
  int* curp2 = (int*)alloc((size_t)S * 4);
  int* pcsr1 = (int*)alloc((size_t)N * 4);
  int* pcsr2 = (int*)alloc((size_t)N * 4);
  u16* PCb = (u16*)alloc((size_t)S * 512 * 2);
  u16* PH  = (u16*)alloc((size_t)S * 256 * 2);
  // transposed bf16 weights
  u16* w11t  = (u16*)alloc((size_t)256 * 128 * 2);
  u16* w12t  = (u16*)alloc((size_t)256 * 128 * 2);
  u16* m1w1t = (u16*)alloc((size_t)256 * 512 * 2);
  u16* m1w2t = (u16*)alloc((size_t)256 * 256 * 2);
  u16* w21t  = (u16*)alloc((size_t)256 * 256 * 2);
  u16* w22t  = (u16*)alloc((size_t)256 * 256 * 2);
  u16* m2w1t = (u16*)alloc((size_t)256 * 512 * 2);
  u16* m2w2t = (u16*)alloc((size_t)256 * 256 * 2);
  u16* mw1t  = (u16*)alloc((size_t)256 * 512 * 2);
  size_t p_base = p;
  u16* xb = (u16*)alloc((size_t)N * 128 * 2);   // bf16 copy of x (optional)
  bool use_xb = (p <= ws_size);
  if (p_base > ws_size) return; // ws too small: fail cleanly, not a fault

  constexpr int NB_N = (N + SCAN_CH - 1) / SCAN_CH; // 49
  constexpr int NB_S = (S + SCAN_CH - 1) / SCAN_CH; // 3

  auto gemm = [&](const u16* A1, int lda1, int K1, const u16* A2, int lda2, int K2,
                  const u16* Wt, const float* bias, u16* Cc, int M, int relu) {
    hipLaunchKernelGGL(mfma_gemm_kernel, dim3(2, (M + 127) / 128), dim3(256), 0, stream,
                       A1, lda1, K1, A2, lda2, K2, Wt, bias, Cc, 256, M, relu);
  };

  // ---- batched weight transposes ----
  {
    WtJobs jobs;
    const float* Ws[9] = {w11, w12, m1w1, m1w2, w21, w22, m2w1, m2w2, mw1};
    u16* Wts[9] = {w11t, w12t, m1w1t, m1w2t, w21t, w22t, m2w1t, m2w2t, mw1t};
    int Ks[9] = {128, 128, 512, 256, 256, 256, 512, 256, 512};
    int acc = 0;
    for (int j = 0; j < 9; j++) {
      jobs.W[j] = Ws[j]; jobs.Wt[j] = Wts[j]; jobs.K[j] = Ks[j];
      jobs.boff[j] = acc; acc += Ks[j];
    }
    jobs.boff[9] = acc; // 2816
    hipLaunchKernelGGL(wt_batch_kernel, dim3(acc), dim3(256), 0, stream, jobs);
  }

  // ---- edge CSRs (both graphs batched via blockIdx.y) ----
  hipMemsetAsync(cntE, 0, (size_t)2 * N * sizeof(int), stream);
  hipLaunchKernelGGL(hist2_kernel, dim3((E + 255) / 256, 2), dim3(256), 0, stream,
                     ei1 + E, cnt1, ei2 + E, cnt2, E);
  hipLaunchKernelGGL(dis2_kernel, dim3((N + 255) / 256, 2), dim3(256), 0, stream,
                     cnt1, dis1, cnt2, dis2);
  hipLaunchKernelGGL(scan_sum2_kernel, dim3(NB_N, 2), dim3(256), 0, stream,
                     cnt1, cnt2, bsum, N);
  hipLaunchKernelGGL(scan_bsum2_kernel, dim3(1), dim3(1), 0, stream, bsum, NB_N);
  hipLaunchKernelGGL(scan_final2_kernel, dim3(NB_N, 2), dim3(256), 0, stream,
                     cnt1, off1, cur1, cnt2, off2, cur2, bsum, N);
  hipLaunchKernelGGL(csr_scatter2_kernel, dim3((E + 255) / 256, 2), dim3(256), 0, stream,
                     ei1, cur1, csr1, ei2, cur2, csr2);

  // ---- pooling CSRs (both index sets batched) ----
  hipMemsetAsync(cntP, 0, (size_t)2 * S * sizeof(int), stream);
  hipLaunchKernelGGL(hist2_kernel, dim3((N + 255) / 256, 2), dim3(256), 0, stream,
                     idx1, cntp1, idx2, cntp2, N);
  hipLaunchKernelGGL(scan_sum2_kernel, dim3(NB_S, 2), dim3(256), 0, stream,
                     cntp1, cntp2, bsum, S);
  hipLaunchKernelGGL(scan_bsum2_kernel, dim3(1), dim3(1), 0, stream, bsum, NB_S);
  hipLaunchKernelGGL(scan_final2_kernel, dim3(NB_S, 2), dim3(256), 0, stream,
                     cntp1, offp1, curp1, cntp2, offp2, curp2, bsum, S);
  hipLaunchKernelGGL(pool_scatter2_kernel, dim3((N + 255) / 256, 2), dim3(256), 0, stream,
                     idx1, curp1, pcsr1, idx2, curp2, pcsr2);

  // ---- layer 1: conv = agg-then-GEMM (A@(XW) == (A@X)@W) ----
  if (use_xb) {
    hipLaunchKernelGGL(f32_to_b16_kernel, dim3((N * 128 / 4 + 255) / 256), dim3(256), 0, stream,
                       x, xb, N * 128 / 4);
    // both graphs in one launch: agg1(x)->B2, agg2(x)->B3 (2 nodes/wave, D=128)
    hipLaunchKernelGGL((agg2_kernel<32>), dim3((N / 2 + 3) / 4, 2), dim3(256), 0, stream,
                       xb, 128, B2, B3,
                       off1, cnt1, csr1, dis1, off2, cnt2, csr2, dis2);
  } else {
    hipLaunchKernelGGL(agg_f32_kernel, dim3(N / 4), dim3(256), 0, stream,
                       x, 128, B2, 128, off1, cnt1, csr1, dis1, 32);
    hipLaunchKernelGGL(agg_f32_kernel, dim3(N / 4), dim3(256), 0, stream,
                       x, 128, B3, 128, off2, cnt2, csr2, dis2, 32);
  }
  gemm(B2, 128, 128, nullptr, 0, 0, w11t, b11, B1, N, 1);        // x1 -> B1
  gemm(B3, 128, 128, nullptr, 0, 0, w12t, b12, B2, N, 1);        // x2 -> B2
  // mlp_1
  gemm(B1, 256, 256, B2, 256, 256, m1w1t, m1b1, B3, N, 1);       // Hm -> B3
  gemm(B3, 256, 256, nullptr, 0, 0, m1w2t, m1b2, B1, N, 0);      // h  -> B1

  // ---- layer 2: both aggs in one launch: agg1(h)->B2, agg2(h)->B3 ----
  hipLaunchKernelGGL((agg2_kernel<64>), dim3((N + 3) / 4, 2), dim3(256), 0, stream,
                     B1, 256, B2, B3,
                     off1, cnt1, csr1, dis1, off2, cnt2, csr2, dis2);
  gemm(B2, 256, 256, nullptr, 0, 0, w21t, b21, B1, N, 1);        // y1 -> B1 (h dead)
  gemm(B3, 256, 256, nullptr, 0, 0, w22t, b22, B2, N, 1);        // y2 -> B2
  // mlp_2
  gemm(B1, 256, 256, B2, 256, 256, m2w1t, m2b1, B3, N, 1);       // Hm2 -> B3
  gemm(B3, 256, 256, nullptr, 0, 0, m2w2t, m2b2, B1, N, 0);      // h2 -> B1

  // ---- pooling: deterministic gather-reduce, both sets in one launch ----
  hipLaunchKernelGGL(pool_gather2_kernel, dim3((S + 3) / 4, 2), dim3(256), 0, stream,
                     B1, offp1, cntp1, pcsr1, offp2, cntp2, pcsr2, PCb);

  // ---- classifier head ----
  gemm(PCb, 512, 512, nullptr, 0, 0, mw1t, mb1, PH, S, 1);
  hipLaunchKernelGGL(final_kernel, dim3((S + 3) / 4), dim3(256), 0, stream,
                     PH, mw2, mb2, out);
}